// Round 1
// baseline (4245.163 us; speedup 1.0000x reference)
//
#include <hip/hip_runtime.h>
#include <cstdint>
#include <cstddef>

#define T_TOK 8192
#define HDIM  2048
#define IDIM  4096
#define NEXP  8

typedef __bf16 bf16x8 __attribute__((ext_vector_type(8)));
typedef float  f32x4  __attribute__((ext_vector_type(4)));

__device__ __forceinline__ unsigned short f2bf(float f) {
    union { float f; unsigned u; } v; v.f = f;
    unsigned r = v.u + 0x7FFFu + ((v.u >> 16) & 1u);   // round-to-nearest-even
    return (unsigned short)(r >> 16);
}

__device__ __forceinline__ void gload16(const void* g, void* l) {
    __builtin_amdgcn_global_load_lds((__attribute__((address_space(1))) void*)g,
                                     (__attribute__((address_space(3))) void*)l,
                                     16, 0, 0);
}

// ---------------- router: one wave per token ----------------
__global__ __launch_bounds__(256) void router_k(const float* __restrict__ hs,
                                                const float* __restrict__ rw,
                                                float* __restrict__ wgt) {
    int gid  = blockIdx.x * 256 + threadIdx.x;
    int tok  = gid >> 6;
    int lane = threadIdx.x & 63;
    const float* x = hs + (size_t)tok * HDIM;

    float acc[NEXP];
#pragma unroll
    for (int e = 0; e < NEXP; ++e) acc[e] = 0.f;

    for (int h = lane; h < HDIM; h += 64) {
        float xv = x[h];
#pragma unroll
        for (int e = 0; e < NEXP; ++e) acc[e] = fmaf(xv, rw[e * HDIM + h], acc[e]);
    }
#pragma unroll
    for (int off = 32; off > 0; off >>= 1) {
#pragma unroll
        for (int e = 0; e < NEXP; ++e) acc[e] += __shfl_xor(acc[e], off, 64);
    }
    if (lane == 0) {
        float m = acc[0];
#pragma unroll
        for (int e = 1; e < NEXP; ++e) m = fmaxf(m, acc[e]);
        float p[NEXP]; float s = 0.f;
#pragma unroll
        for (int e = 0; e < NEXP; ++e) { p[e] = expf(acc[e] - m); s += p[e]; }
        float inv = 1.f / s;
        int i1 = 0;
#pragma unroll
        for (int e = 1; e < NEXP; ++e) if (acc[e] > acc[i1]) i1 = e;
        int i2 = -1;
#pragma unroll
        for (int e = 0; e < NEXP; ++e) if (e != i1 && (i2 < 0 || acc[e] > acc[i2])) i2 = e;
#pragma unroll
        for (int e = 0; e < NEXP; ++e)
            wgt[(size_t)tok * NEXP + e] = (e == i1 || e == i2) ? p[e] * inv : 0.f;
    }
}

// ---------------- fp32 -> bf16 conversion, vectorized ----------------
__global__ __launch_bounds__(256) void cvt_k(const float* __restrict__ in,
                                             unsigned short* __restrict__ out, long n4) {
    long i      = (long)blockIdx.x * 256 + threadIdx.x;
    long stride = (long)gridDim.x * 256;
    const float4* in4 = (const float4*)in;
    ushort4* out4 = (ushort4*)out;
    for (long j = i; j < n4; j += stride) {
        float4 v = in4[j];
        ushort4 o;
        o.x = f2bf(v.x); o.y = f2bf(v.y); o.z = f2bf(v.z); o.w = f2bf(v.w);
        out4[j] = o;
    }
}

// ---------------- GEMM1: h = silu(hs @ Wg^T) * (hs @ Wu^T), bf16 out ----------------
// BM=128, BN=64 (intermediate dim), BK=32, 256 threads = 4 waves (2x2), wave tile 64x32 (x2 acc sets)
__global__ __launch_bounds__(256, 2) void gemm1_k(const unsigned short* __restrict__ A,  // hs bf16 [T][H]
                                                  const unsigned short* __restrict__ W,  // ws_e bf16 [2I][H]
                                                  unsigned short* __restrict__ Hout) {   // [T][I]
    __shared__ __align__(16) unsigned short As[128 * 32];
    __shared__ __align__(16) unsigned short Bg[64 * 32];
    __shared__ __align__(16) unsigned short Bu[64 * 32];

    const int tid = threadIdx.x;
    const int lane = tid & 63;
    const int wid = tid >> 6;
    const int wr = wid >> 1, wc = wid & 1;
    const int t0 = blockIdx.x * 128;
    const int n0 = blockIdx.y * 64;

    f32x4 accg[4][2], accu[4][2];
#pragma unroll
    for (int mi = 0; mi < 4; ++mi)
#pragma unroll
        for (int ni = 0; ni < 2; ++ni) {
            accg[mi][ni] = (f32x4){0.f, 0.f, 0.f, 0.f};
            accu[mi][ni] = (f32x4){0.f, 0.f, 0.f, 0.f};
        }

    // staging geometry: A tile 128x32 (2 passes of 256 threads x 8 elems), B tiles 64x32 (1 pass)
    const int aeo0 = tid * 8;
    const int aeo1 = 2048 + tid * 8;
    const int ar0 = aeo0 >> 5, ac0 = aeo0 & 31;
    const int ar1 = aeo1 >> 5, ac1 = aeo1 & 31;
    const int br = tid >> 2, bc = (tid & 3) * 8;

    const size_t Ab0 = (size_t)(t0 + ar0) * HDIM + ac0;
    const size_t Ab1 = (size_t)(t0 + ar1) * HDIM + ac1;
    const size_t Gb  = (size_t)(n0 + br) * HDIM + bc;
    const size_t Ub  = (size_t)(IDIM + n0 + br) * HDIM + bc;

    for (int k0 = 0; k0 < HDIM; k0 += 32) {
        gload16(A + Ab0 + k0, &As[aeo0]);
        gload16(A + Ab1 + k0, &As[aeo1]);
        gload16(W + Gb + k0, &Bg[tid * 8]);
        gload16(W + Ub + k0, &Bu[tid * 8]);
        __syncthreads();

        bf16x8 af[4], gf[2], uf[2];
#pragma unroll
        for (int mi = 0; mi < 4; ++mi)
            af[mi] = *(const bf16x8*)&As[(wr * 64 + mi * 16 + (lane & 15)) * 32 + (lane >> 4) * 8];
#pragma unroll
        for (int ni = 0; ni < 2; ++ni) {
            gf[ni] = *(const bf16x8*)&Bg[(wc * 32 + ni * 16 + (lane & 15)) * 32 + (lane >> 4) * 8];
            uf[ni] = *(const bf16x8*)&Bu[(wc * 32 + ni * 16 + (lane & 15)) * 32 + (lane >> 4) * 8];
        }
#pragma unroll
        for (int mi = 0; mi < 4; ++mi)
#pragma unroll
            for (int ni = 0; ni < 2; ++ni) {
                accg[mi][ni] = __builtin_amdgcn_mfma_f32_16x16x32_bf16(af[mi], gf[ni], accg[mi][ni], 0, 0, 0);
                accu[mi][ni] = __builtin_amdgcn_mfma_f32_16x16x32_bf16(af[mi], uf[ni], accu[mi][ni], 0, 0, 0);
            }
        __syncthreads();
    }

#pragma unroll
    for (int mi = 0; mi < 4; ++mi)
#pragma unroll
        for (int ni = 0; ni < 2; ++ni)
#pragma unroll
            for (int j = 0; j < 4; ++j) {
                int row = t0 + wr * 64 + mi * 16 + ((lane >> 4) << 2) + j;
                int col = n0 + wc * 32 + ni * 16 + (lane & 15);
                float g = accg[mi][ni][j], u = accu[mi][ni][j];
                float hv = (g / (1.f + expf(-g))) * u;
                Hout[(size_t)row * IDIM + col] = f2bf(hv);
            }
}

// ---------------- GEMM2: out += wgt[:,e] * (h @ w2^T) ----------------
// BM=128, BN=128, BK=32, 256 threads = 4 waves (2x2), wave tile 64x64 (m97 structure)
__global__ __launch_bounds__(256, 2) void gemm2_k(const unsigned short* __restrict__ A,  // h bf16 [T][I]
                                                  const unsigned short* __restrict__ B,  // w2 bf16 [H][I]
                                                  const float* __restrict__ wgt,
                                                  float* __restrict__ out, int e) {
    __shared__ __align__(16) unsigned short As[128 * 32];
    __shared__ __align__(16) unsigned short Bs[128 * 32];

    const int tid = threadIdx.x;
    const int lane = tid & 63;
    const int wid = tid >> 6;
    const int wr = wid >> 1, wc = wid & 1;
    const int t0 = blockIdx.x * 128;
    const int n0 = blockIdx.y * 128;

    f32x4 acc[4][4];
#pragma unroll
    for (int mi = 0; mi < 4; ++mi)
#pragma unroll
        for (int ni = 0; ni < 4; ++ni) acc[mi][ni] = (f32x4){0.f, 0.f, 0.f, 0.f};

    const int eo0 = tid * 8;
    const int eo1 = 2048 + tid * 8;
    const int r0 = eo0 >> 5, c0 = eo0 & 31;
    const int r1 = eo1 >> 5, c1 = eo1 & 31;
    const size_t Ab0 = (size_t)(t0 + r0) * IDIM + c0;
    const size_t Ab1 = (size_t)(t0 + r1) * IDIM + c1;
    const size_t Bb0 = (size_t)(n0 + r0) * IDIM + c0;
    const size_t Bb1 = (size_t)(n0 + r1) * IDIM + c1;

    for (int k0 = 0; k0 < IDIM; k0 += 32) {
        gload16(A + Ab0 + k0, &As[eo0]);
        gload16(A + Ab1 + k0, &As[eo1]);
        gload16(B + Bb0 + k0, &Bs[eo0]);
        gload16(B + Bb1 + k0, &Bs[eo1]);
        __syncthreads();

        bf16x8 af[4], bfr[4];
#pragma unroll
        for (int mi = 0; mi < 4; ++mi)
            af[mi] = *(const bf16x8*)&As[(wr * 64 + mi * 16 + (lane & 15)) * 32 + (lane >> 4) * 8];
#pragma unroll
        for (int ni = 0; ni < 4; ++ni)
            bfr[ni] = *(const bf16x8*)&Bs[(wc * 64 + ni * 16 + (lane & 15)) * 32 + (lane >> 4) * 8];
#pragma unroll
        for (int mi = 0; mi < 4; ++mi)
#pragma unroll
            for (int ni = 0; ni < 4; ++ni)
                acc[mi][ni] = __builtin_amdgcn_mfma_f32_16x16x32_bf16(af[mi], bfr[ni], acc[mi][ni], 0, 0, 0);
        __syncthreads();
    }

#pragma unroll
    for (int mi = 0; mi < 4; ++mi)
#pragma unroll
        for (int j = 0; j < 4; ++j) {
            int row = t0 + wr * 64 + mi * 16 + ((lane >> 4) << 2) + j;
            float w = wgt[(size_t)row * NEXP + e];
            if (w != 0.f) {
#pragma unroll
                for (int ni = 0; ni < 4; ++ni) {
                    int col = n0 + wc * 64 + ni * 16 + (lane & 15);
                    float* o = out + (size_t)row * HDIM + col;
                    *o += w * acc[mi][ni][j];
                }
            }
        }
}

extern "C" void kernel_launch(void* const* d_in, const int* in_sizes, int n_in,
                              void* d_out, int out_size, void* d_ws, size_t ws_size,
                              hipStream_t stream) {
    const float* hs  = (const float*)d_in[0];
    const float* rw  = (const float*)d_in[1];
    const float* ws  = (const float*)d_in[2];
    const float* w2s = (const float*)d_in[3];
    float* out = (float*)d_out;

    char* wsp = (char*)d_ws;
    unsigned short* hs_bf = (unsigned short*)(wsp);               // 33,554,432 B
    float*          wgt   = (float*)(wsp + 33554432);             //    262,144 B
    unsigned short* w_bf  = (unsigned short*)(wsp + 33816576);    // 33,554,432 B
    unsigned short* w2_bf = (unsigned short*)(wsp + 67371008);    // 16,777,216 B
    unsigned short* h_bf  = (unsigned short*)(wsp + 84148224);    // 67,108,864 B
    // total workspace: 151,257,088 B

    hipMemsetAsync(d_out, 0, (size_t)T_TOK * HDIM * sizeof(float), stream);
    cvt_k<<<2048, 256, 0, stream>>>(hs, hs_bf, (long)T_TOK * HDIM / 4);
    router_k<<<(T_TOK * 64) / 256, 256, 0, stream>>>(hs, rw, wgt);

    for (int e = 0; e < NEXP; ++e) {
        const float* we  = ws + (size_t)e * 2 * IDIM * HDIM;
        const float* w2e = w2s + (size_t)e * HDIM * IDIM;
        cvt_k<<<2048, 256, 0, stream>>>(we, w_bf, (long)2 * IDIM * HDIM / 4);
        cvt_k<<<2048, 256, 0, stream>>>(w2e, w2_bf, (long)HDIM * IDIM / 4);
        gemm1_k<<<dim3(T_TOK / 128, IDIM / 64), 256, 0, stream>>>(hs_bf, w_bf, h_bf);
        gemm2_k<<<dim3(T_TOK / 128, HDIM / 128), 256, 0, stream>>>(h_bf, w2_bf, wgt, out, e);
    }
}

// Round 2
// 2845.675 us; speedup vs baseline: 1.4918x; 1.4918x over previous
//
#include <hip/hip_runtime.h>
#include <cstdint>
#include <cstddef>

#define T_TOK 8192
#define HDIM  2048
#define IDIM  4096
#define NEXP  8

typedef __bf16 bf16x8 __attribute__((ext_vector_type(8)));
typedef float  f32x4  __attribute__((ext_vector_type(4)));

__device__ __forceinline__ unsigned short f2bf(float f) {
    union { float f; unsigned u; } v; v.f = f;
    unsigned r = v.u + 0x7FFFu + ((v.u >> 16) & 1u);   // round-to-nearest-even
    return (unsigned short)(r >> 16);
}

__device__ __forceinline__ void gload16(const void* g, void* l) {
    __builtin_amdgcn_global_load_lds((__attribute__((address_space(1))) void*)g,
                                     (__attribute__((address_space(3))) void*)l,
                                     16, 0, 0);
}

// ---------------- router: one wave per token; builds dense wgt + per-expert lists ----------------
__global__ __launch_bounds__(256) void router_k(const float* __restrict__ hs,
                                                const float* __restrict__ rw,
                                                float* __restrict__ wgt,
                                                int* __restrict__ counts,
                                                int* __restrict__ lists) {
    int gid  = blockIdx.x * 256 + threadIdx.x;
    int tok  = gid >> 6;
    int lane = threadIdx.x & 63;
    const float* x = hs + (size_t)tok * HDIM;

    float acc[NEXP];
#pragma unroll
    for (int e = 0; e < NEXP; ++e) acc[e] = 0.f;

    for (int h = lane; h < HDIM; h += 64) {
        float xv = x[h];
#pragma unroll
        for (int e = 0; e < NEXP; ++e) acc[e] = fmaf(xv, rw[e * HDIM + h], acc[e]);
    }
#pragma unroll
    for (int off = 32; off > 0; off >>= 1) {
#pragma unroll
        for (int e = 0; e < NEXP; ++e) acc[e] += __shfl_xor(acc[e], off, 64);
    }
    if (lane == 0) {
        float m = acc[0];
#pragma unroll
        for (int e = 1; e < NEXP; ++e) m = fmaxf(m, acc[e]);
        float p[NEXP]; float s = 0.f;
#pragma unroll
        for (int e = 0; e < NEXP; ++e) { p[e] = expf(acc[e] - m); s += p[e]; }
        float inv = 1.f / s;
        int i1 = 0;
#pragma unroll
        for (int e = 1; e < NEXP; ++e) if (acc[e] > acc[i1]) i1 = e;   // ties -> lowest idx (matches top_k)
        int i2 = -1;
#pragma unroll
        for (int e = 0; e < NEXP; ++e) if (e != i1 && (i2 < 0 || acc[e] > acc[i2])) i2 = e;
#pragma unroll
        for (int e = 0; e < NEXP; ++e)
            wgt[(size_t)tok * NEXP + e] = (e == i1 || e == i2) ? p[e] * inv : 0.f;
        int p1 = atomicAdd(&counts[i1], 1);
        lists[i1 * T_TOK + p1] = tok;
        int p2 = atomicAdd(&counts[i2], 1);
        lists[i2 * T_TOK + p2] = tok;
    }
}

// ---------------- fp32 -> bf16 conversion, vectorized ----------------
__global__ __launch_bounds__(256) void cvt_k(const float* __restrict__ in,
                                             unsigned short* __restrict__ out, long n4) {
    long i      = (long)blockIdx.x * 256 + threadIdx.x;
    long stride = (long)gridDim.x * 256;
    const float4* in4 = (const float4*)in;
    ushort4* out4 = (ushort4*)out;
    for (long j = i; j < n4; j += stride) {
        float4 v = in4[j];
        ushort4 o;
        o.x = f2bf(v.x); o.y = f2bf(v.y); o.z = f2bf(v.z); o.w = f2bf(v.w);
        out4[j] = o;
    }
}

// ---------------- GEMM1 (gathered): h[p] = silu(hs[list[p]] @ Wg^T) * (hs[list[p]] @ Wu^T) ----------------
// BM=128, BN=64, BK=32, 256 threads = 4 waves (2x2); A rows gathered via list
__global__ __launch_bounds__(256, 2) void gemm1_k(const unsigned short* __restrict__ A,  // hs bf16 [T][H]
                                                  const unsigned short* __restrict__ W,  // ws_e bf16 [2I][H]
                                                  unsigned short* __restrict__ Hout,     // [cap][I] compact
                                                  const int* __restrict__ list,
                                                  const int* __restrict__ cntp) {
    const int cnt = *cntp;
    const int t0 = blockIdx.x * 128;
    if (t0 >= cnt) return;

    __shared__ __align__(16) unsigned short As[128 * 32];
    __shared__ __align__(16) unsigned short Bg[64 * 32];
    __shared__ __align__(16) unsigned short Bu[64 * 32];

    const int tid = threadIdx.x;
    const int lane = tid & 63;
    const int wid = tid >> 6;
    const int wr = wid >> 1, wc = wid & 1;
    const int n0 = blockIdx.y * 64;

    f32x4 accg[4][2], accu[4][2];
#pragma unroll
    for (int mi = 0; mi < 4; ++mi)
#pragma unroll
        for (int ni = 0; ni < 2; ++ni) {
            accg[mi][ni] = (f32x4){0.f, 0.f, 0.f, 0.f};
            accu[mi][ni] = (f32x4){0.f, 0.f, 0.f, 0.f};
        }

    const int aeo0 = tid * 8;
    const int aeo1 = 2048 + tid * 8;
    const int ar0 = aeo0 >> 5, ac0 = aeo0 & 31;
    const int ar1 = aeo1 >> 5, ac1 = aeo1 & 31;
    const int br = tid >> 2, bc = (tid & 3) * 8;

    // gather: clamp pad rows to token 0 (finite data; results discarded downstream)
    const int tok0 = (t0 + ar0 < cnt) ? list[t0 + ar0] : list[t0];
    const int tok1 = (t0 + ar1 < cnt) ? list[t0 + ar1] : list[t0];
    const size_t Ab0 = (size_t)tok0 * HDIM + ac0;
    const size_t Ab1 = (size_t)tok1 * HDIM + ac1;
    const size_t Gb  = (size_t)(n0 + br) * HDIM + bc;
    const size_t Ub  = (size_t)(IDIM + n0 + br) * HDIM + bc;

    for (int k0 = 0; k0 < HDIM; k0 += 32) {
        gload16(A + Ab0 + k0, &As[aeo0]);
        gload16(A + Ab1 + k0, &As[aeo1]);
        gload16(W + Gb + k0, &Bg[tid * 8]);
        gload16(W + Ub + k0, &Bu[tid * 8]);
        __syncthreads();

        bf16x8 af[4], gf[2], uf[2];
#pragma unroll
        for (int mi = 0; mi < 4; ++mi)
            af[mi] = *(const bf16x8*)&As[(wr * 64 + mi * 16 + (lane & 15)) * 32 + (lane >> 4) * 8];
#pragma unroll
        for (int ni = 0; ni < 2; ++ni) {
            gf[ni] = *(const bf16x8*)&Bg[(wc * 32 + ni * 16 + (lane & 15)) * 32 + (lane >> 4) * 8];
            uf[ni] = *(const bf16x8*)&Bu[(wc * 32 + ni * 16 + (lane & 15)) * 32 + (lane >> 4) * 8];
        }
#pragma unroll
        for (int mi = 0; mi < 4; ++mi)
#pragma unroll
            for (int ni = 0; ni < 2; ++ni) {
                accg[mi][ni] = __builtin_amdgcn_mfma_f32_16x16x32_bf16(af[mi], gf[ni], accg[mi][ni], 0, 0, 0);
                accu[mi][ni] = __builtin_amdgcn_mfma_f32_16x16x32_bf16(af[mi], uf[ni], accu[mi][ni], 0, 0, 0);
            }
        __syncthreads();
    }

#pragma unroll
    for (int mi = 0; mi < 4; ++mi)
#pragma unroll
        for (int ni = 0; ni < 2; ++ni)
#pragma unroll
            for (int j = 0; j < 4; ++j) {
                int row = t0 + wr * 64 + mi * 16 + ((lane >> 4) << 2) + j;
                int col = n0 + wc * 32 + ni * 16 + (lane & 15);
                float g = accg[mi][ni][j], u = accu[mi][ni][j];
                float hv = (g / (1.f + expf(-g))) * u;
                Hout[(size_t)row * IDIM + col] = f2bf(hv);
            }
}

// ---------------- GEMM2 (scattered): out[list[p]] += wgt[list[p]][e] * (h[p] @ w2^T) ----------------
// BM=128, BN=128, BK=32, 256 threads = 4 waves (2x2)
__global__ __launch_bounds__(256, 2) void gemm2_k(const unsigned short* __restrict__ A,  // h bf16 compact
                                                  const unsigned short* __restrict__ B,  // w2 bf16 [H][I]
                                                  const float* __restrict__ wgt,
                                                  float* __restrict__ out,
                                                  const int* __restrict__ list,
                                                  const int* __restrict__ cntp, int e) {
    const int cnt = *cntp;
    const int t0 = blockIdx.x * 128;
    if (t0 >= cnt) return;

    __shared__ __align__(16) unsigned short As[128 * 32];
    __shared__ __align__(16) unsigned short Bs[128 * 32];

    const int tid = threadIdx.x;
    const int lane = tid & 63;
    const int wid = tid >> 6;
    const int wr = wid >> 1, wc = wid & 1;
    const int n0 = blockIdx.y * 128;

    f32x4 acc[4][4];
#pragma unroll
    for (int mi = 0; mi < 4; ++mi)
#pragma unroll
        for (int ni = 0; ni < 4; ++ni) acc[mi][ni] = (f32x4){0.f, 0.f, 0.f, 0.f};

    const int eo0 = tid * 8;
    const int eo1 = 2048 + tid * 8;
    const int r0 = eo0 >> 5, c0 = eo0 & 31;
    const int r1 = eo1 >> 5, c1 = eo1 & 31;
    const size_t Ab0 = (size_t)(t0 + r0) * IDIM + c0;
    const size_t Ab1 = (size_t)(t0 + r1) * IDIM + c1;
    const size_t Bb0 = (size_t)(n0 + r0) * IDIM + c0;
    const size_t Bb1 = (size_t)(n0 + r1) * IDIM + c1;

    for (int k0 = 0; k0 < IDIM; k0 += 32) {
        gload16(A + Ab0 + k0, &As[eo0]);
        gload16(A + Ab1 + k0, &As[eo1]);
        gload16(B + Bb0 + k0, &Bs[eo0]);
        gload16(B + Bb1 + k0, &Bs[eo1]);
        __syncthreads();

        bf16x8 af[4], bfr[4];
#pragma unroll
        for (int mi = 0; mi < 4; ++mi)
            af[mi] = *(const bf16x8*)&As[(wr * 64 + mi * 16 + (lane & 15)) * 32 + (lane >> 4) * 8];
#pragma unroll
        for (int ni = 0; ni < 4; ++ni)
            bfr[ni] = *(const bf16x8*)&Bs[(wc * 64 + ni * 16 + (lane & 15)) * 32 + (lane >> 4) * 8];
#pragma unroll
        for (int mi = 0; mi < 4; ++mi)
#pragma unroll
            for (int ni = 0; ni < 4; ++ni)
                acc[mi][ni] = __builtin_amdgcn_mfma_f32_16x16x32_bf16(af[mi], bfr[ni], acc[mi][ni], 0, 0, 0);
        __syncthreads();
    }

#pragma unroll
    for (int mi = 0; mi < 4; ++mi)
#pragma unroll
        for (int j = 0; j < 4; ++j) {
            int row_l = wr * 64 + mi * 16 + ((lane >> 4) << 2) + j;
            int g = t0 + row_l;
            if (g < cnt) {
                int tok = list[g];
                float w = wgt[(size_t)tok * NEXP + e];
#pragma unroll
                for (int ni = 0; ni < 4; ++ni) {
                    int col = n0 + wc * 64 + ni * 16 + (lane & 15);
                    float* o = out + (size_t)tok * HDIM + col;
                    *o += w * acc[mi][ni][j];
                }
            }
        }
}

extern "C" void kernel_launch(void* const* d_in, const int* in_sizes, int n_in,
                              void* d_out, int out_size, void* d_ws, size_t ws_size,
                              hipStream_t stream) {
    const float* hs  = (const float*)d_in[0];
    const float* rw  = (const float*)d_in[1];
    const float* ws  = (const float*)d_in[2];
    const float* w2s = (const float*)d_in[3];
    float* out = (float*)d_out;

    char* wsp = (char*)d_ws;
    unsigned short* hs_bf = (unsigned short*)(wsp);               // 33,554,432 B
    float*          wgt   = (float*)(wsp + 33554432);             //    262,144 B
    unsigned short* w_bf  = (unsigned short*)(wsp + 33816576);    // 33,554,432 B
    unsigned short* w2_bf = (unsigned short*)(wsp + 67371008);    // 16,777,216 B
    unsigned short* h_bf  = (unsigned short*)(wsp + 84148224);    // 67,108,864 B
    int*            counts = (int*)(wsp + 151257088);             //         32 B
    int*            lists  = (int*)(wsp + 151257216);             //    262,144 B
    // total workspace: ~151.6 MB

    hipMemsetAsync(d_out, 0, (size_t)T_TOK * HDIM * sizeof(float), stream);
    hipMemsetAsync(counts, 0, NEXP * sizeof(int), stream);
    cvt_k<<<2048, 256, 0, stream>>>(hs, hs_bf, (long)T_TOK * HDIM / 4);
    router_k<<<(T_TOK * 64) / 256, 256, 0, stream>>>(hs, rw, wgt, counts, lists);

    for (int e = 0; e < NEXP; ++e) {
        const float* we  = ws + (size_t)e * 2 * IDIM * HDIM;
        const float* w2e = w2s + (size_t)e * HDIM * IDIM;
        cvt_k<<<2048, 256, 0, stream>>>(we, w_bf, (long)2 * IDIM * HDIM / 4);
        cvt_k<<<2048, 256, 0, stream>>>(w2e, w2_bf, (long)HDIM * IDIM / 4);
        gemm1_k<<<dim3(T_TOK / 128, IDIM / 64), 256, 0, stream>>>(
            hs_bf, w_bf, h_bf, lists + e * T_TOK, counts + e);
        gemm2_k<<<dim3(T_TOK / 128, HDIM / 128), 256, 0, stream>>>(
            h_bf, w2_bf, wgt, out, lists + e * T_TOK, counts + e, e);
    }
}

// Round 3
// 2189.990 us; speedup vs baseline: 1.9384x; 1.2994x over previous
//
#include <hip/hip_runtime.h>
#include <cstdint>
#include <cstddef>

#define T_TOK 8192
#define HDIM  2048
#define IDIM  4096
#define NEXP  8
#define MAXTILES 136   // sum_e ceil(cnt_e/128) <= 16384/128 + 7 = 135

typedef __bf16 bf16x8 __attribute__((ext_vector_type(8)));
typedef float  f32x4  __attribute__((ext_vector_type(4)));

__device__ __forceinline__ unsigned short f2bf(float f) {
    union { float f; unsigned u; } v; v.f = f;
    unsigned r = v.u + 0x7FFFu + ((v.u >> 16) & 1u);   // round-to-nearest-even
    return (unsigned short)(r >> 16);
}

__device__ __forceinline__ void gload16(const void* g, void* l) {
    __builtin_amdgcn_global_load_lds((__attribute__((address_space(1))) void*)g,
                                     (__attribute__((address_space(3))) void*)l,
                                     16, 0, 0);
}

// ---------------- router: one wave per token; wgt + per-expert lists (slot-tagged) ----------------
__global__ __launch_bounds__(256) void router_k(const float* __restrict__ hs,
                                                const float* __restrict__ rw,
                                                float* __restrict__ wgt,
                                                int* __restrict__ counts,
                                                int* __restrict__ lists) {
    int gid  = blockIdx.x * 256 + threadIdx.x;
    int tok  = gid >> 6;
    int lane = threadIdx.x & 63;
    const float* x = hs + (size_t)tok * HDIM;

    float acc[NEXP];
#pragma unroll
    for (int e = 0; e < NEXP; ++e) acc[e] = 0.f;

    for (int h = lane; h < HDIM; h += 64) {
        float xv = x[h];
#pragma unroll
        for (int e = 0; e < NEXP; ++e) acc[e] = fmaf(xv, rw[e * HDIM + h], acc[e]);
    }
#pragma unroll
    for (int off = 32; off > 0; off >>= 1) {
#pragma unroll
        for (int e = 0; e < NEXP; ++e) acc[e] += __shfl_xor(acc[e], off, 64);
    }
    if (lane == 0) {
        float m = acc[0];
#pragma unroll
        for (int e = 1; e < NEXP; ++e) m = fmaxf(m, acc[e]);
        float p[NEXP]; float s = 0.f;
#pragma unroll
        for (int e = 0; e < NEXP; ++e) { p[e] = expf(acc[e] - m); s += p[e]; }
        float inv = 1.f / s;
        int i1 = 0;
#pragma unroll
        for (int e = 1; e < NEXP; ++e) if (acc[e] > acc[i1]) i1 = e;   // ties -> lowest idx
        int i2 = -1;
#pragma unroll
        for (int e = 0; e < NEXP; ++e) if (e != i1 && (i2 < 0 || acc[e] > acc[i2])) i2 = e;
#pragma unroll
        for (int e = 0; e < NEXP; ++e)
            wgt[(size_t)tok * NEXP + e] = (e == i1 || e == i2) ? p[e] * inv : 0.f;
        int p1 = atomicAdd(&counts[i1], 1);
        lists[i1 * T_TOK + p1] = tok;                 // slot 0
        int p2 = atomicAdd(&counts[i2], 1);
        lists[i2 * T_TOK + p2] = (1 << 16) | tok;     // slot 1
    }
}

// ---------------- planner: counts -> flat tile descriptors + padded h-row offsets ----------------
__global__ void plan_k(const int* __restrict__ counts, int* __restrict__ offs,
                       int* __restrict__ desc, int* __restrict__ ntiles) {
    if (threadIdx.x == 0 && blockIdx.x == 0) {
        int off = 0, n = 0;
        for (int e = 0; e < NEXP; ++e) {
            offs[e] = off;
            int nt = (counts[e] + 127) >> 7;
            for (int t = 0; t < nt; ++t) desc[n++] = (e << 16) | t;
            off += nt * 128;
        }
        *ntiles = n;
    }
}

// ---------------- fp32 -> bf16 conversion, vectorized ----------------
__global__ __launch_bounds__(256) void cvt_k(const float* __restrict__ in,
                                             unsigned short* __restrict__ out, long n4) {
    long i      = (long)blockIdx.x * 256 + threadIdx.x;
    long stride = (long)gridDim.x * 256;
    const float4* in4 = (const float4*)in;
    ushort4* out4 = (ushort4*)out;
    for (long j = i; j < n4; j += stride) {
        float4 v = in4[j];
        ushort4 o;
        o.x = f2bf(v.x); o.y = f2bf(v.y); o.z = f2bf(v.z); o.w = f2bf(v.w);
        out4[j] = o;
    }
}

// ---------------- GEMM1 (all experts, gathered): h = silu(gate)*up, bf16 compact ----------------
__global__ __launch_bounds__(256, 2) void gemm1_k(const unsigned short* __restrict__ A,    // hs bf16 [T][H]
                                                  const unsigned short* __restrict__ Wall, // bf16 [E][2I][H]
                                                  unsigned short* __restrict__ Hout,       // compact padded
                                                  const int* __restrict__ lists,
                                                  const int* __restrict__ counts,
                                                  const int* __restrict__ offs,
                                                  const int* __restrict__ desc,
                                                  const int* __restrict__ ntiles) {
    const int slot = blockIdx.x;
    if (slot >= *ntiles) return;
    const int dsc = desc[slot];
    const int e = dsc >> 16, tt = dsc & 0xFFFF;
    const int cnt = counts[e];
    const int t0 = tt * 128;
    const int* list = lists + e * T_TOK;
    const unsigned short* W = Wall + (size_t)e * 2 * IDIM * HDIM;
    const int hbase = offs[e];

    __shared__ __align__(16) unsigned short As[128 * 32];
    __shared__ __align__(16) unsigned short Bg[64 * 32];
    __shared__ __align__(16) unsigned short Bu[64 * 32];

    const int tid = threadIdx.x;
    const int lane = tid & 63;
    const int wid = tid >> 6;
    const int wr = wid >> 1, wc = wid & 1;
    const int n0 = blockIdx.y * 64;

    f32x4 accg[4][2], accu[4][2];
#pragma unroll
    for (int mi = 0; mi < 4; ++mi)
#pragma unroll
        for (int ni = 0; ni < 2; ++ni) {
            accg[mi][ni] = (f32x4){0.f, 0.f, 0.f, 0.f};
            accu[mi][ni] = (f32x4){0.f, 0.f, 0.f, 0.f};
        }

    const int aeo0 = tid * 8;
    const int aeo1 = 2048 + tid * 8;
    const int ar0 = aeo0 >> 5, ac0 = aeo0 & 31;
    const int ar1 = aeo1 >> 5, ac1 = aeo1 & 31;
    const int br = tid >> 2, bc = (tid & 3) * 8;

    const int tok0 = ((t0 + ar0 < cnt) ? list[t0 + ar0] : list[t0]) & 0xFFFF;
    const int tok1 = ((t0 + ar1 < cnt) ? list[t0 + ar1] : list[t0]) & 0xFFFF;
    const size_t Ab0 = (size_t)tok0 * HDIM + ac0;
    const size_t Ab1 = (size_t)tok1 * HDIM + ac1;
    const size_t Gb  = (size_t)(n0 + br) * HDIM + bc;
    const size_t Ub  = (size_t)(IDIM + n0 + br) * HDIM + bc;

    for (int k0 = 0; k0 < HDIM; k0 += 32) {
        gload16(A + Ab0 + k0, &As[aeo0]);
        gload16(A + Ab1 + k0, &As[aeo1]);
        gload16(W + Gb + k0, &Bg[tid * 8]);
        gload16(W + Ub + k0, &Bu[tid * 8]);
        __syncthreads();

        bf16x8 af[4], gf[2], uf[2];
#pragma unroll
        for (int mi = 0; mi < 4; ++mi)
            af[mi] = *(const bf16x8*)&As[(wr * 64 + mi * 16 + (lane & 15)) * 32 + (lane >> 4) * 8];
#pragma unroll
        for (int ni = 0; ni < 2; ++ni) {
            gf[ni] = *(const bf16x8*)&Bg[(wc * 32 + ni * 16 + (lane & 15)) * 32 + (lane >> 4) * 8];
            uf[ni] = *(const bf16x8*)&Bu[(wc * 32 + ni * 16 + (lane & 15)) * 32 + (lane >> 4) * 8];
        }
#pragma unroll
        for (int mi = 0; mi < 4; ++mi)
#pragma unroll
            for (int ni = 0; ni < 2; ++ni) {
                accg[mi][ni] = __builtin_amdgcn_mfma_f32_16x16x32_bf16(af[mi], gf[ni], accg[mi][ni], 0, 0, 0);
                accu[mi][ni] = __builtin_amdgcn_mfma_f32_16x16x32_bf16(af[mi], uf[ni], accu[mi][ni], 0, 0, 0);
            }
        __syncthreads();
    }

#pragma unroll
    for (int mi = 0; mi < 4; ++mi)
#pragma unroll
        for (int ni = 0; ni < 2; ++ni)
#pragma unroll
            for (int j = 0; j < 4; ++j) {
                int row = hbase + t0 + wr * 64 + mi * 16 + ((lane >> 4) << 2) + j;
                int col = n0 + wc * 32 + ni * 16 + (lane & 15);
                float g = accg[mi][ni][j], u = accu[mi][ni][j];
                float hv = (g / (1.f + expf(-g))) * u;
                Hout[(size_t)row * IDIM + col] = f2bf(hv);
            }
}

// ---------------- GEMM2 (all experts): outP[slot][tok] = wgt*(h @ w2^T), exclusive stores ----------------
__global__ __launch_bounds__(256, 2) void gemm2_k(const unsigned short* __restrict__ A,    // h bf16 compact
                                                  const unsigned short* __restrict__ Ball, // w2 bf16 [E][H][I]
                                                  const float* __restrict__ wgt,
                                                  float* __restrict__ outP,                // [2][T][H]
                                                  const int* __restrict__ lists,
                                                  const int* __restrict__ counts,
                                                  const int* __restrict__ offs,
                                                  const int* __restrict__ desc,
                                                  const int* __restrict__ ntiles) {
    const int slot = blockIdx.x;
    if (slot >= *ntiles) return;
    const int dsc = desc[slot];
    const int e = dsc >> 16, tt = dsc & 0xFFFF;
    const int cnt = counts[e];
    const int t0 = tt * 128;
    const int* list = lists + e * T_TOK;
    const unsigned short* B = Ball + (size_t)e * HDIM * IDIM;
    const int hbase = offs[e];

    __shared__ __align__(16) unsigned short As[128 * 32];
    __shared__ __align__(16) unsigned short Bs[128 * 32];

    const int tid = threadIdx.x;
    const int lane = tid & 63;
    const int wid = tid >> 6;
    const int wr = wid >> 1, wc = wid & 1;
    const int n0 = blockIdx.y * 128;

    f32x4 acc[4][4];
#pragma unroll
    for (int mi = 0; mi < 4; ++mi)
#pragma unroll
        for (int ni = 0; ni < 4; ++ni) acc[mi][ni] = (f32x4){0.f, 0.f, 0.f, 0.f};

    const int eo0 = tid * 8;
    const int eo1 = 2048 + tid * 8;
    const int r0 = eo0 >> 5, c0 = eo0 & 31;
    const int r1 = eo1 >> 5, c1 = eo1 & 31;
    const size_t Ab0 = (size_t)(hbase + t0 + r0) * IDIM + c0;
    const size_t Ab1 = (size_t)(hbase + t0 + r1) * IDIM + c1;
    const size_t Bb0 = (size_t)(n0 + r0) * IDIM + c0;
    const size_t Bb1 = (size_t)(n0 + r1) * IDIM + c1;

    for (int k0 = 0; k0 < IDIM; k0 += 32) {
        gload16(A + Ab0 + k0, &As[eo0]);
        gload16(A + Ab1 + k0, &As[eo1]);
        gload16(B + Bb0 + k0, &Bs[eo0]);
        gload16(B + Bb1 + k0, &Bs[eo1]);
        __syncthreads();

        bf16x8 af[4], bfr[4];
#pragma unroll
        for (int mi = 0; mi < 4; ++mi)
            af[mi] = *(const bf16x8*)&As[(wr * 64 + mi * 16 + (lane & 15)) * 32 + (lane >> 4) * 8];
#pragma unroll
        for (int ni = 0; ni < 4; ++ni)
            bfr[ni] = *(const bf16x8*)&Bs[(wc * 64 + ni * 16 + (lane & 15)) * 32 + (lane >> 4) * 8];
#pragma unroll
        for (int mi = 0; mi < 4; ++mi)
#pragma unroll
            for (int ni = 0; ni < 4; ++ni)
                acc[mi][ni] = __builtin_amdgcn_mfma_f32_16x16x32_bf16(af[mi], bfr[ni], acc[mi][ni], 0, 0, 0);
        __syncthreads();
    }

#pragma unroll
    for (int mi = 0; mi < 4; ++mi)
#pragma unroll
        for (int j = 0; j < 4; ++j) {
            int row_l = wr * 64 + mi * 16 + ((lane >> 4) << 2) + j;
            int g = t0 + row_l;
            if (g < cnt) {
                int ent = list[g];
                int tok = ent & 0xFFFF;
                int sl  = ent >> 16;
                float w = wgt[(size_t)tok * NEXP + e];
                float* o = outP + (size_t)sl * T_TOK * HDIM + (size_t)tok * HDIM;
#pragma unroll
                for (int ni = 0; ni < 4; ++ni) {
                    int col = n0 + wc * 64 + ni * 16 + (lane & 15);
                    o[col] = w * acc[mi][ni][j];
                }
            }
        }
}

// ---------------- combine: out = outP[0] + outP[1] ----------------
__global__ __launch_bounds__(256) void combine_k(const float* __restrict__ p0,
                                                 const float* __restrict__ p1,
                                                 float* __restrict__ out, long n4) {
    long i      = (long)blockIdx.x * 256 + threadIdx.x;
    long stride = (long)gridDim.x * 256;
    const float4* a4 = (const float4*)p0;
    const float4* b4 = (const float4*)p1;
    float4* o4 = (float4*)out;
    for (long j = i; j < n4; j += stride) {
        float4 a = a4[j], b = b4[j];
        o4[j] = make_float4(a.x + b.x, a.y + b.y, a.z + b.z, a.w + b.w);
    }
}

extern "C" void kernel_launch(void* const* d_in, const int* in_sizes, int n_in,
                              void* d_out, int out_size, void* d_ws, size_t ws_size,
                              hipStream_t stream) {
    const float* hs  = (const float*)d_in[0];
    const float* rw  = (const float*)d_in[1];
    const float* ws  = (const float*)d_in[2];
    const float* w2s = (const float*)d_in[3];
    float* out = (float*)d_out;

    char* wsp = (char*)d_ws;
    unsigned short* hs_bf = (unsigned short*)(wsp);                 // 33,554,432
    unsigned short* w_bf  = (unsigned short*)(wsp + 33554432ULL);   // 268,435,456
    unsigned short* w2_bf = (unsigned short*)(wsp + 301989888ULL);  // 134,217,728
    unsigned short* h_bf  = (unsigned short*)(wsp + 436207616ULL);  // 142,606,336 (17408 rows x IDIM)
    float*          outP  = (float*)(wsp + 578813952ULL);           // 134,217,728
    float*          wgt   = (float*)(wsp + 713031680ULL);           //     262,144
    int*            counts = (int*)(wsp + 713293824ULL);            //          32
    int*            offs   = (int*)(wsp + 713293856ULL);            //          32
    int*            lists  = (int*)(wsp + 713293888ULL);            //     262,144
    int*            desc   = (int*)(wsp + 713556032ULL);            //         544
    int*            ntiles = (int*)(wsp + 713556608ULL);            //           4
    // total ~713.6 MB (< 2 GiB workspace)

    hipMemsetAsync(counts, 0, NEXP * sizeof(int), stream);
    cvt_k<<<2048, 256, 0, stream>>>(hs, hs_bf, (long)T_TOK * HDIM / 4);
    cvt_k<<<4096, 256, 0, stream>>>(ws, w_bf, (long)NEXP * 2 * IDIM * HDIM / 4);
    cvt_k<<<4096, 256, 0, stream>>>(w2s, w2_bf, (long)NEXP * HDIM * IDIM / 4);
    router_k<<<(T_TOK * 64) / 256, 256, 0, stream>>>(hs, rw, wgt, counts, lists);
    plan_k<<<1, 64, 0, stream>>>(counts, offs, desc, ntiles);

    gemm1_k<<<dim3(MAXTILES, IDIM / 64), 256, 0, stream>>>(
        hs_bf, w_bf, h_bf, lists, counts, offs, desc, ntiles);
    gemm2_k<<<dim3(MAXTILES, HDIM / 128), 256, 0, stream>>>(
        h_bf, w2_bf, wgt, outP, lists, counts, offs, desc, ntiles);
    combine_k<<<2048, 256, 0, stream>>>(outP, outP + (size_t)T_TOK * HDIM, out,
                                        (long)T_TOK * HDIM / 4);
}

// Round 4
// 1599.187 us; speedup vs baseline: 2.6546x; 1.3694x over previous
//
#include <hip/hip_runtime.h>
#include <cstdint>
#include <cstddef>

#define T_TOK 8192
#define HDIM  2048
#define IDIM  4096
#define NEXP  8
#define MAXTILES 136   // sum_e ceil(cnt_e/128) <= 16384/128 + 7 = 135

typedef __bf16 bf16x8 __attribute__((ext_vector_type(8)));
typedef float  f32x4  __attribute__((ext_vector_type(4)));

__device__ __forceinline__ unsigned short f2bf(float f) {
    union { float f; unsigned u; } v; v.f = f;
    unsigned r = v.u + 0x7FFFu + ((v.u >> 16) & 1u);   // round-to-nearest-even
    return (unsigned short)(r >> 16);
}

__device__ __forceinline__ void gload16(const void* g, void* l) {
    __builtin_amdgcn_global_load_lds((__attribute__((address_space(1))) void*)g,
                                     (__attribute__((address_space(3))) void*)l,
                                     16, 0, 0);
}

// ---------------- router: one wave per token; wgt + per-expert lists (slot-tagged) ----------------
__global__ __launch_bounds__(256) void router_k(const float* __restrict__ hs,
                                                const float* __restrict__ rw,
                                                float* __restrict__ wgt,
                                                int* __restrict__ counts,
                                                int* __restrict__ lists) {
    int gid  = blockIdx.x * 256 + threadIdx.x;
    int tok  = gid >> 6;
    int lane = threadIdx.x & 63;
    const float* x = hs + (size_t)tok * HDIM;

    float acc[NEXP];
#pragma unroll
    for (int e = 0; e < NEXP; ++e) acc[e] = 0.f;

    for (int h = lane; h < HDIM; h += 64) {
        float xv = x[h];
#pragma unroll
        for (int e = 0; e < NEXP; ++e) acc[e] = fmaf(xv, rw[e * HDIM + h], acc[e]);
    }
#pragma unroll
    for (int off = 32; off > 0; off >>= 1) {
#pragma unroll
        for (int e = 0; e < NEXP; ++e) acc[e] += __shfl_xor(acc[e], off, 64);
    }
    if (lane == 0) {
        float m = acc[0];
#pragma unroll
        for (int e = 1; e < NEXP; ++e) m = fmaxf(m, acc[e]);
        float p[NEXP]; float s = 0.f;
#pragma unroll
        for (int e = 0; e < NEXP; ++e) { p[e] = expf(acc[e] - m); s += p[e]; }
        float inv = 1.f / s;
        int i1 = 0;
#pragma unroll
        for (int e = 1; e < NEXP; ++e) if (acc[e] > acc[i1]) i1 = e;   // ties -> lowest idx
        int i2 = -1;
#pragma unroll
        for (int e = 0; e < NEXP; ++e) if (e != i1 && (i2 < 0 || acc[e] > acc[i2])) i2 = e;
#pragma unroll
        for (int e = 0; e < NEXP; ++e)
            wgt[(size_t)tok * NEXP + e] = (e == i1 || e == i2) ? p[e] * inv : 0.f;
        int p1 = atomicAdd(&counts[i1], 1);
        lists[i1 * T_TOK + p1] = tok;                 // slot 0
        int p2 = atomicAdd(&counts[i2], 1);
        lists[i2 * T_TOK + p2] = (1 << 16) | tok;     // slot 1
    }
}

// ---------------- planner: counts -> flat tile descriptors + padded h-row offsets ----------------
__global__ void plan_k(const int* __restrict__ counts, int* __restrict__ offs,
                       int* __restrict__ desc, int* __restrict__ ntiles) {
    if (threadIdx.x == 0 && blockIdx.x == 0) {
        int off = 0, n = 0;
        for (int e = 0; e < NEXP; ++e) {
            offs[e] = off;
            int nt = (counts[e] + 127) >> 7;
            for (int t = 0; t < nt; ++t) desc[n++] = (e << 16) | t;
            off += nt * 128;
        }
        *ntiles = n;
    }
}

// ---------------- fp32 -> bf16 conversion, vectorized ----------------
__global__ __launch_bounds__(256) void cvt_k(const float* __restrict__ in,
                                             unsigned short* __restrict__ out, long n4) {
    long i      = (long)blockIdx.x * 256 + threadIdx.x;
    long stride = (long)gridDim.x * 256;
    const float4* in4 = (const float4*)in;
    ushort4* out4 = (ushort4*)out;
    for (long j = i; j < n4; j += stride) {
        float4 v = in4[j];
        ushort4 o;
        o.x = f2bf(v.x); o.y = f2bf(v.y); o.z = f2bf(v.z); o.w = f2bf(v.w);
        out4[j] = o;
    }
}

// ---------------- GEMM1 (all experts, gathered, FUSED gate+up): 128x128 tile ----------------
// grid: (x = IDIM/128 n-tiles [inner, shares A-tile in cache], y = slot)
__global__ __launch_bounds__(256, 2) void gemm1_k(const unsigned short* __restrict__ A,    // hs bf16 [T][H]
                                                  const unsigned short* __restrict__ Wall, // bf16 [E][2I][H]
                                                  unsigned short* __restrict__ Hout,       // compact padded [*][I]
                                                  const int* __restrict__ lists,
                                                  const int* __restrict__ counts,
                                                  const int* __restrict__ offs,
                                                  const int* __restrict__ desc,
                                                  const int* __restrict__ ntiles) {
    const int slot = blockIdx.y;
    if (slot >= *ntiles) return;
    const int dsc = desc[slot];
    const int e = dsc >> 16, tt = dsc & 0xFFFF;
    const int cnt = counts[e];
    const int t0 = tt * 128;
    const int* list = lists + e * T_TOK;
    const unsigned short* W = Wall + (size_t)e * 2 * IDIM * HDIM;
    const int hbase = offs[e];
    const int n0 = blockIdx.x * 128;

    __shared__ __align__(16) unsigned short As[128 * 32];
    __shared__ __align__(16) unsigned short Bg[128 * 32];
    __shared__ __align__(16) unsigned short Bu[128 * 32];

    const int tid = threadIdx.x;
    const int lane = tid & 63;
    const int wid = tid >> 6;
    const int wr = wid >> 1, wc = wid & 1;

    f32x4 accg[4][4], accu[4][4];
#pragma unroll
    for (int mi = 0; mi < 4; ++mi)
#pragma unroll
        for (int ni = 0; ni < 4; ++ni) {
            accg[mi][ni] = (f32x4){0.f, 0.f, 0.f, 0.f};
            accu[mi][ni] = (f32x4){0.f, 0.f, 0.f, 0.f};
        }

    const int eo0 = tid * 8;              // rows 0..63
    const int eo1 = 2048 + tid * 8;       // rows 64..127
    const int r0 = eo0 >> 5, c0 = eo0 & 31;
    const int r1 = eo1 >> 5, c1 = eo1 & 31;

    const int tok0 = ((t0 + r0 < cnt) ? list[t0 + r0] : list[t0]) & 0xFFFF;
    const int tok1 = ((t0 + r1 < cnt) ? list[t0 + r1] : list[t0]) & 0xFFFF;
    const size_t Ab0 = (size_t)tok0 * HDIM + c0;
    const size_t Ab1 = (size_t)tok1 * HDIM + c1;
    const size_t Gb0 = (size_t)(n0 + r0) * HDIM + c0;
    const size_t Gb1 = (size_t)(n0 + r1) * HDIM + c1;
    const size_t Ub0 = (size_t)(IDIM + n0 + r0) * HDIM + c0;
    const size_t Ub1 = (size_t)(IDIM + n0 + r1) * HDIM + c1;

    for (int k0 = 0; k0 < HDIM; k0 += 32) {
        gload16(A + Ab0 + k0, &As[eo0]);
        gload16(A + Ab1 + k0, &As[eo1]);
        gload16(W + Gb0 + k0, &Bg[eo0]);
        gload16(W + Gb1 + k0, &Bg[eo1]);
        gload16(W + Ub0 + k0, &Bu[eo0]);
        gload16(W + Ub1 + k0, &Bu[eo1]);
        __syncthreads();

        bf16x8 af[4], gf[4], uf[4];
#pragma unroll
        for (int mi = 0; mi < 4; ++mi)
            af[mi] = *(const bf16x8*)&As[(wr * 64 + mi * 16 + (lane & 15)) * 32 + (lane >> 4) * 8];
#pragma unroll
        for (int ni = 0; ni < 4; ++ni) {
            gf[ni] = *(const bf16x8*)&Bg[(wc * 64 + ni * 16 + (lane & 15)) * 32 + (lane >> 4) * 8];
            uf[ni] = *(const bf16x8*)&Bu[(wc * 64 + ni * 16 + (lane & 15)) * 32 + (lane >> 4) * 8];
        }
#pragma unroll
        for (int mi = 0; mi < 4; ++mi)
#pragma unroll
            for (int ni = 0; ni < 4; ++ni) {
                accg[mi][ni] = __builtin_amdgcn_mfma_f32_16x16x32_bf16(af[mi], gf[ni], accg[mi][ni], 0, 0, 0);
                accu[mi][ni] = __builtin_amdgcn_mfma_f32_16x16x32_bf16(af[mi], uf[ni], accu[mi][ni], 0, 0, 0);
            }
        __syncthreads();
    }

#pragma unroll
    for (int mi = 0; mi < 4; ++mi)
#pragma unroll
        for (int ni = 0; ni < 4; ++ni)
#pragma unroll
            for (int j = 0; j < 4; ++j) {
                int row = hbase + t0 + wr * 64 + mi * 16 + ((lane >> 4) << 2) + j;
                int col = n0 + wc * 64 + ni * 16 + (lane & 15);
                float g = accg[mi][ni][j], u = accu[mi][ni][j];
                float hv = (g / (1.f + expf(-g))) * u;
                Hout[(size_t)row * IDIM + col] = f2bf(hv);
            }
}

// ---------------- GEMM2 (all experts): outP[slot][tok] = wgt*(h @ w2^T), exclusive stores ----------------
// grid: (x = HDIM/128 n-tiles [inner], y = slot)
__global__ __launch_bounds__(256, 2) void gemm2_k(const unsigned short* __restrict__ A,    // h bf16 compact
                                                  const unsigned short* __restrict__ Ball, // w2 bf16 [E][H][I]
                                                  const float* __restrict__ wgt,
                                                  float* __restrict__ outP,                // [2][T][H]
                                                  const int* __restrict__ lists,
                                                  const int* __restrict__ counts,
                                                  const int* __restrict__ offs,
                                                  const int* __restrict__ desc,
                                                  const int* __restrict__ ntiles) {
    const int slot = blockIdx.y;
    if (slot >= *ntiles) return;
    const int dsc = desc[slot];
    const int e = dsc >> 16, tt = dsc & 0xFFFF;
    const int cnt = counts[e];
    const int t0 = tt * 128;
    const int* list = lists + e * T_TOK;
    const unsigned short* B = Ball + (size_t)e * HDIM * IDIM;
    const int hbase = offs[e];
    const int n0 = blockIdx.x * 128;

    __shared__ __align__(16) unsigned short As[128 * 32];
    __shared__ __align__(16) unsigned short Bs[128 * 32];

    const int tid = threadIdx.x;
    const int lane = tid & 63;
    const int wid = tid >> 6;
    const int wr = wid >> 1, wc = wid & 1;

    f32x4 acc[4][4];
#pragma unroll
    for (int mi = 0; mi < 4; ++mi)
#pragma unroll
        for (int ni = 0; ni < 4; ++ni) acc[mi][ni] = (f32x4){0.f, 0.f, 0.f, 0.f};

    const int eo0 = tid * 8;
    const int eo1 = 2048 + tid * 8;
    const int r0 = eo0 >> 5, c0 = eo0 & 31;
    const int r1 = eo1 >> 5, c1 = eo1 & 31;
    const size_t Ab0 = (size_t)(hbase + t0 + r0) * IDIM + c0;
    const size_t Ab1 = (size_t)(hbase + t0 + r1) * IDIM + c1;
    const size_t Bb0 = (size_t)(n0 + r0) * IDIM + c0;
    const size_t Bb1 = (size_t)(n0 + r1) * IDIM + c1;

    for (int k0 = 0; k0 < IDIM; k0 += 32) {
        gload16(A + Ab0 + k0, &As[eo0]);
        gload16(A + Ab1 + k0, &As[eo1]);
        gload16(B + Bb0 + k0, &Bs[eo0]);
        gload16(B + Bb1 + k0, &Bs[eo1]);
        __syncthreads();

        bf16x8 af[4], bfr[4];
#pragma unroll
        for (int mi = 0; mi < 4; ++mi)
            af[mi] = *(const bf16x8*)&As[(wr * 64 + mi * 16 + (lane & 15)) * 32 + (lane >> 4) * 8];
#pragma unroll
        for (int ni = 0; ni < 4; ++ni)
            bfr[ni] = *(const bf16x8*)&Bs[(wc * 64 + ni * 16 + (lane & 15)) * 32 + (lane >> 4) * 8];
#pragma unroll
        for (int mi = 0; mi < 4; ++mi)
#pragma unroll
            for (int ni = 0; ni < 4; ++ni)
                acc[mi][ni] = __builtin_amdgcn_mfma_f32_16x16x32_bf16(af[mi], bfr[ni], acc[mi][ni], 0, 0, 0);
        __syncthreads();
    }

#pragma unroll
    for (int mi = 0; mi < 4; ++mi)
#pragma unroll
        for (int j = 0; j < 4; ++j) {
            int row_l = wr * 64 + mi * 16 + ((lane >> 4) << 2) + j;
            int g = t0 + row_l;
            if (g < cnt) {
                int ent = list[g];
                int tok = ent & 0xFFFF;
                int sl  = ent >> 16;
                float w = wgt[(size_t)tok * NEXP + e];
                float* o = outP + (size_t)sl * T_TOK * HDIM + (size_t)tok * HDIM;
#pragma unroll
                for (int ni = 0; ni < 4; ++ni) {
                    int col = n0 + wc * 64 + ni * 16 + (lane & 15);
                    o[col] = w * acc[mi][ni][j];
                }
            }
        }
}

// ---------------- combine: out = outP[0] + outP[1] ----------------
__global__ __launch_bounds__(256) void combine_k(const float* __restrict__ p0,
                                                 const float* __restrict__ p1,
                                                 float* __restrict__ out, long n4) {
    long i      = (long)blockIdx.x * 256 + threadIdx.x;
    long stride = (long)gridDim.x * 256;
    const float4* a4 = (const float4*)p0;
    const float4* b4 = (const float4*)p1;
    float4* o4 = (float4*)out;
    for (long j = i; j < n4; j += stride) {
        float4 a = a4[j], b = b4[j];
        o4[j] = make_float4(a.x + b.x, a.y + b.y, a.z + b.z, a.w + b.w);
    }
}

extern "C" void kernel_launch(void* const* d_in, const int* in_sizes, int n_in,
                              void* d_out, int out_size, void* d_ws, size_t ws_size,
                              hipStream_t stream) {
    const float* hs  = (const float*)d_in[0];
    const float* rw  = (const float*)d_in[1];
    const float* ws  = (const float*)d_in[2];
    const float* w2s = (const float*)d_in[3];
    float* out = (float*)d_out;

    char* wsp = (char*)d_ws;
    unsigned short* hs_bf = (unsigned short*)(wsp);                 // 33,554,432
    unsigned short* w_bf  = (unsigned short*)(wsp + 33554432ULL);   // 268,435,456
    unsigned short* w2_bf = (unsigned short*)(wsp + 301989888ULL);  // 134,217,728
    unsigned short* h_bf  = (unsigned short*)(wsp + 436207616ULL);  // 142,606,336 (17408 rows x IDIM)
    float*          outP  = (float*)(wsp + 578813952ULL);           // 134,217,728
    float*          wgt   = (float*)(wsp + 713031680ULL);           //     262,144
    int*            counts = (int*)(wsp + 713293824ULL);            //          32
    int*            offs   = (int*)(wsp + 713293856ULL);            //          32
    int*            lists  = (int*)(wsp + 713293888ULL);            //     262,144
    int*            desc   = (int*)(wsp + 713556032ULL);            //         544
    int*            ntiles = (int*)(wsp + 713556608ULL);            //           4
    // total ~713.6 MB

    hipMemsetAsync(counts, 0, NEXP * sizeof(int), stream);
    cvt_k<<<2048, 256, 0, stream>>>(hs, hs_bf, (long)T_TOK * HDIM / 4);
    cvt_k<<<4096, 256, 0, stream>>>(ws, w_bf, (long)NEXP * 2 * IDIM * HDIM / 4);
    cvt_k<<<4096, 256, 0, stream>>>(w2s, w2_bf, (long)NEXP * HDIM * IDIM / 4);
    router_k<<<(T_TOK * 64) / 256, 256, 0, stream>>>(hs, rw, wgt, counts, lists);
    plan_k<<<1, 64, 0, stream>>>(counts, offs, desc, ntiles);

    gemm1_k<<<dim3(IDIM / 128, MAXTILES), 256, 0, stream>>>(
        hs_bf, w_bf, h_bf, lists, counts, offs, desc, ntiles);
    gemm2_k<<<dim3(HDIM / 128, MAXTILES), 256, 0, stream>>>(
        h_bf, w2_bf, wgt, outP, lists, counts, offs, desc, ntiles);
    combine_k<<<2048, 256, 0, stream>>>(outP, outP + (size_t)T_TOK * HDIM, out,
                                        (long)T_TOK * HDIM / 4);
}

// Round 5
// 1592.366 us; speedup vs baseline: 2.6659x; 1.0043x over previous
//
#include <hip/hip_runtime.h>
#include <cstdint>
#include <cstddef>

#define T_TOK 8192
#define HDIM  2048
#define IDIM  4096
#define NEXP  8
#define MAXT  72   // sum_e ceil(cnt_e/256) <= 16384/256 + 7 = 71

typedef __bf16 bf16x8 __attribute__((ext_vector_type(8)));
typedef float  f32x4  __attribute__((ext_vector_type(4)));

#define BARRIER() __builtin_amdgcn_s_barrier()
#define LGKM0()   do { asm volatile("s_waitcnt lgkmcnt(0)" ::: "memory"); __builtin_amdgcn_sched_barrier(0); } while (0)
#define VMW(n)    do { asm volatile("s_waitcnt vmcnt(" #n ")" ::: "memory"); } while (0)

__device__ __forceinline__ unsigned short f2bf(float f) {
    union { float f; unsigned u; } v; v.f = f;
    unsigned r = v.u + 0x7FFFu + ((v.u >> 16) & 1u);   // RNE
    return (unsigned short)(r >> 16);
}

__device__ __forceinline__ void gload16(const void* g, void* l) {
    __builtin_amdgcn_global_load_lds((__attribute__((address_space(1))) void*)g,
                                     (__attribute__((address_space(3))) void*)l,
                                     16, 0, 0);
}

// ---------------- router ----------------
__global__ __launch_bounds__(256) void router_k(const float* __restrict__ hs,
                                                const float* __restrict__ rw,
                                                float* __restrict__ wgt,
                                                int* __restrict__ counts,
                                                int* __restrict__ lists) {
    int gid  = blockIdx.x * 256 + threadIdx.x;
    int tok  = gid >> 6;
    int lane = threadIdx.x & 63;
    const float* x = hs + (size_t)tok * HDIM;

    float acc[NEXP];
#pragma unroll
    for (int e = 0; e < NEXP; ++e) acc[e] = 0.f;
    for (int h = lane; h < HDIM; h += 64) {
        float xv = x[h];
#pragma unroll
        for (int e = 0; e < NEXP; ++e) acc[e] = fmaf(xv, rw[e * HDIM + h], acc[e]);
    }
#pragma unroll
    for (int off = 32; off > 0; off >>= 1) {
#pragma unroll
        for (int e = 0; e < NEXP; ++e) acc[e] += __shfl_xor(acc[e], off, 64);
    }
    if (lane == 0) {
        float m = acc[0];
#pragma unroll
        for (int e = 1; e < NEXP; ++e) m = fmaxf(m, acc[e]);
        float p[NEXP]; float s = 0.f;
#pragma unroll
        for (int e = 0; e < NEXP; ++e) { p[e] = expf(acc[e] - m); s += p[e]; }
        float inv = 1.f / s;
        int i1 = 0;
#pragma unroll
        for (int e = 1; e < NEXP; ++e) if (acc[e] > acc[i1]) i1 = e;
        int i2 = -1;
#pragma unroll
        for (int e = 0; e < NEXP; ++e) if (e != i1 && (i2 < 0 || acc[e] > acc[i2])) i2 = e;
#pragma unroll
        for (int e = 0; e < NEXP; ++e)
            wgt[(size_t)tok * NEXP + e] = (e == i1 || e == i2) ? p[e] * inv : 0.f;
        int p1 = atomicAdd(&counts[i1], 1);
        lists[i1 * T_TOK + p1] = tok;                 // slot 0
        int p2 = atomicAdd(&counts[i2], 1);
        lists[i2 * T_TOK + p2] = (1 << 16) | tok;     // slot 1
    }
}

// ---------------- planner (256-row granularity) ----------------
__global__ void plan_k(const int* __restrict__ counts, int* __restrict__ offs,
                       int* __restrict__ desc, int* __restrict__ ntiles) {
    if (threadIdx.x == 0 && blockIdx.x == 0) {
        int off = 0, n = 0;
        for (int e = 0; e < NEXP; ++e) {
            offs[e] = off;
            int nt = (counts[e] + 255) >> 8;
            for (int t = 0; t < nt; ++t) desc[n++] = (e << 16) | t;
            off += nt * 256;
        }
        *ntiles = n;
    }
}

// ---------------- fp32 -> bf16 ----------------
__global__ __launch_bounds__(256) void cvt_k(const float* __restrict__ in,
                                             unsigned short* __restrict__ out, long n4) {
    long i      = (long)blockIdx.x * 256 + threadIdx.x;
    long stride = (long)gridDim.x * 256;
    const float4* in4 = (const float4*)in;
    ushort4* out4 = (ushort4*)out;
    for (long j = i; j < n4; j += stride) {
        float4 v = in4[j];
        ushort4 o;
        o.x = f2bf(v.x); o.y = f2bf(v.y); o.z = f2bf(v.z); o.w = f2bf(v.w);
        out4[j] = o;
    }
}

// ============ GEMM1: fused gate/up, BM=256 BN=128 BK=64, 8 waves, dbuf+counted vmcnt ============
// LDS: A [buf2][half2][16KB] @0 ; Bg @65536+buf*16384 ; Bu @98304+buf*16384  (128 KiB)
__global__ __launch_bounds__(512, 2) void gemm1_k(const unsigned short* __restrict__ A,
                                                  const unsigned short* __restrict__ Wall,
                                                  unsigned short* __restrict__ Hout,
                                                  const int* __restrict__ lists,
                                                  const int* __restrict__ counts,
                                                  const int* __restrict__ offs,
                                                  const int* __restrict__ desc,
                                                  const int* __restrict__ ntiles) {
    const int slot = blockIdx.y;
    if (slot >= *ntiles) return;
    const int dsc = desc[slot];
    const int e = dsc >> 16, tt = dsc & 0xFFFF;
    const int cnt = counts[e];
    const int t0 = tt * 256;
    const int* list = lists + e * T_TOK;
    const unsigned short* W = Wall + (size_t)e * 2 * IDIM * HDIM;
    const int hbase = offs[e];
    const int n0 = blockIdx.x * 128;

    extern __shared__ __align__(16) char lds[];

    const int tid  = threadIdx.x;
    const int lane = tid & 63;
    const int wid  = tid >> 6;
    const int wr   = wid >> 2;   // M half (128 rows)
    const int wc   = wid & 3;    // 32-col group

    // ---- staging: pre-swizzled global source, linear LDS dest ----
    const int prow = tid >> 3;                 // 0..63
    const int pcol = (tid & 7) * 16;           // byte within 128B row
    const int fsw  = ((prow & 4) << 3) | ((prow & 8) << 3);
    const int lcol = (pcol ^ fsw) >> 1;        // logical element offset in K-chunk
    unsigned aoff[4];
#pragma unroll
    for (int i = 0; i < 4; ++i) {
        int g = t0 + i * 64 + prow;
        int tok = list[(g < cnt) ? g : t0] & 0xFFFF;
        aoff[i] = (unsigned)tok * HDIM + lcol;
    }
    unsigned goff[2], uoff[2];
#pragma unroll
    for (int i = 0; i < 2; ++i) {
        goff[i] = (unsigned)(n0 + i * 64 + prow) * HDIM + lcol;
        uoff[i] = (unsigned)(IDIM + n0 + i * 64 + prow) * HDIM + lcol;
    }
    const int dst = tid * 16;

#define G1_STAGE(buf, kt) do {                                                     \
    unsigned k0_ = (unsigned)(kt) * 64;                                            \
    _Pragma("unroll") for (int i_ = 0; i_ < 4; ++i_)                               \
        gload16(A + aoff[i_] + k0_, lds + (buf) * 32768 + i_ * 8192 + dst);        \
    _Pragma("unroll") for (int i_ = 0; i_ < 2; ++i_)                               \
        gload16(W + goff[i_] + k0_, lds + 65536 + (buf) * 16384 + i_ * 8192 + dst);\
    _Pragma("unroll") for (int i_ = 0; i_ < 2; ++i_)                               \
        gload16(W + uoff[i_] + k0_, lds + 98304 + (buf) * 16384 + i_ * 8192 + dst);\
} while (0)

    // ---- read-side swizzled addresses ----
    const int frd = (lane & 12) << 3;
    const int cb0 = (((lane >> 4) * 16)      ) ^ frd;
    const int cb1 = (((lane >> 4) * 16) + 64 ) ^ frd;
    const int arow = wr * 16384 + (lane & 15) * 128;            // + mi*2048 + buf*32768
    const int bgrow = 65536 + (wc * 32 + (lane & 15)) * 128;    // + ni*2048 + buf*16384
    const int burow = 98304 + (wc * 32 + (lane & 15)) * 128;

    f32x4 accg[8][2], accu[8][2];
#pragma unroll
    for (int mi = 0; mi < 8; ++mi)
#pragma unroll
        for (int ni = 0; ni < 2; ++ni) {
            accg[mi][ni] = (f32x4){0.f, 0.f, 0.f, 0.f};
            accu[mi][ni] = (f32x4){0.f, 0.f, 0.f, 0.f};
        }

    G1_STAGE(0, 0);
    G1_STAGE(1, 1);
    VMW(8);
    BARRIER();

    const int NT = HDIM / 64;   // 32
    int buf = 0;
    for (int kt = 0; kt < NT; ++kt) {
        const char* la = lds + buf * 32768 + arow;
        const char* lg = lds + buf * 16384 + bgrow;
        const char* lu = lds + buf * 16384 + burow;
        bf16x8 af[2][4], bg[2][2], bu[2][2];
        // ---- S1: read af(mi0-3) + Bg + Bu, MFMA g(M0) ----
#pragma unroll
        for (int mi = 0; mi < 4; ++mi) {
            af[0][mi] = *(const bf16x8*)(la + mi * 2048 + cb0);
            af[1][mi] = *(const bf16x8*)(la + mi * 2048 + cb1);
        }
#pragma unroll
        for (int ni = 0; ni < 2; ++ni) {
            bg[0][ni] = *(const bf16x8*)(lg + ni * 2048 + cb0);
            bg[1][ni] = *(const bf16x8*)(lg + ni * 2048 + cb1);
            bu[0][ni] = *(const bf16x8*)(lu + ni * 2048 + cb0);
            bu[1][ni] = *(const bf16x8*)(lu + ni * 2048 + cb1);
        }
        LGKM0();
        __builtin_amdgcn_s_setprio(1);
#pragma unroll
        for (int ks = 0; ks < 2; ++ks)
#pragma unroll
            for (int mi = 0; mi < 4; ++mi)
#pragma unroll
                for (int ni = 0; ni < 2; ++ni)
                    accg[mi][ni] = __builtin_amdgcn_mfma_f32_16x16x32_bf16(af[ks][mi], bg[ks][ni], accg[mi][ni], 0, 0, 0);
        __builtin_amdgcn_s_setprio(0);
        BARRIER();
        // ---- S2: MFMA u(M0); reload af(mi4-7); MFMA g(M1) ----
        __builtin_amdgcn_s_setprio(1);
#pragma unroll
        for (int ks = 0; ks < 2; ++ks)
#pragma unroll
            for (int mi = 0; mi < 4; ++mi)
#pragma unroll
                for (int ni = 0; ni < 2; ++ni)
                    accu[mi][ni] = __builtin_amdgcn_mfma_f32_16x16x32_bf16(af[ks][mi], bu[ks][ni], accu[mi][ni], 0, 0, 0);
        __builtin_amdgcn_s_setprio(0);
#pragma unroll
        for (int mi = 0; mi < 4; ++mi) {
            af[0][mi] = *(const bf16x8*)(la + (mi + 4) * 2048 + cb0);
            af[1][mi] = *(const bf16x8*)(la + (mi + 4) * 2048 + cb1);
        }
        LGKM0();
        __builtin_amdgcn_s_setprio(1);
#pragma unroll
        for (int ks = 0; ks < 2; ++ks)
#pragma unroll
            for (int mi = 0; mi < 4; ++mi)
#pragma unroll
                for (int ni = 0; ni < 2; ++ni)
                    accg[mi + 4][ni] = __builtin_amdgcn_mfma_f32_16x16x32_bf16(af[ks][mi], bg[ks][ni], accg[mi + 4][ni], 0, 0, 0);
        __builtin_amdgcn_s_setprio(0);
        BARRIER();   // all waves done reading buf
        // ---- S3: stage kt+2 into buf; MFMA u(M1); drain kt+1 ----
        G1_STAGE(buf, (kt + 2) & (NT - 1));
        __builtin_amdgcn_s_setprio(1);
#pragma unroll
        for (int ks = 0; ks < 2; ++ks)
#pragma unroll
            for (int mi = 0; mi < 4; ++mi)
#pragma unroll
                for (int ni = 0; ni < 2; ++ni)
                    accu[mi + 4][ni] = __builtin_amdgcn_mfma_f32_16x16x32_bf16(af[ks][mi], bu[ks][ni], accu[mi + 4][ni], 0, 0, 0);
        __builtin_amdgcn_s_setprio(0);
        VMW(8);
        BARRIER();
        buf ^= 1;
    }
    VMW(0);
#undef G1_STAGE

#pragma unroll
    for (int mi = 0; mi < 8; ++mi)
#pragma unroll
        for (int ni = 0; ni < 2; ++ni)
#pragma unroll
            for (int j = 0; j < 4; ++j) {
                int row = hbase + t0 + wr * 128 + mi * 16 + ((lane >> 4) << 2) + j;
                int col = n0 + wc * 32 + ni * 16 + (lane & 15);
                float g = accg[mi][ni][j], u = accu[mi][ni][j];
                float hv = (g / (1.f + expf(-g))) * u;
                Hout[(size_t)row * IDIM + col] = f2bf(hv);
            }
}

// ============ GEMM2: BM=256 BN=128 BK=64, 8 waves, dbuf+counted vmcnt, scatter epilogue ============
// LDS: A [buf2][half2][16KB] @0 ; B @65536+buf*16384  (96 KiB)
__global__ __launch_bounds__(512, 2) void gemm2_k(const unsigned short* __restrict__ Ah,
                                                  const unsigned short* __restrict__ Ball,
                                                  const float* __restrict__ wgt,
                                                  float* __restrict__ outP,
                                                  const int* __restrict__ lists,
                                                  const int* __restrict__ counts,
                                                  const int* __restrict__ offs,
                                                  const int* __restrict__ desc,
                                                  const int* __restrict__ ntiles) {
    const int slot = blockIdx.y;
    if (slot >= *ntiles) return;
    const int dsc = desc[slot];
    const int e = dsc >> 16, tt = dsc & 0xFFFF;
    const int cnt = counts[e];
    const int t0 = tt * 256;
    const int* list = lists + e * T_TOK;
    const unsigned short* B = Ball + (size_t)e * HDIM * IDIM;
    const int hbase = offs[e];
    const int n0 = blockIdx.x * 128;

    extern __shared__ __align__(16) char lds[];

    const int tid  = threadIdx.x;
    const int lane = tid & 63;
    const int wid  = tid >> 6;
    const int wr   = wid >> 2;
    const int wc   = wid & 3;

    const int prow = tid >> 3;
    const int pcol = (tid & 7) * 16;
    const int fsw  = ((prow & 4) << 3) | ((prow & 8) << 3);
    const int lcol = (pcol ^ fsw) >> 1;
    unsigned aoff[4];
#pragma unroll
    for (int i = 0; i < 4; ++i)
        aoff[i] = (unsigned)(hbase + t0 + i * 64 + prow) * IDIM + lcol;
    unsigned boff[2];
#pragma unroll
    for (int i = 0; i < 2; ++i)
        boff[i] = (unsigned)(n0 + i * 64 + prow) * IDIM + lcol;
    const int dst = tid * 16;

#define G2_STAGE(buf, kt) do {                                                     \
    unsigned k0_ = (unsigned)(kt) * 64;                                            \
    _Pragma("unroll") for (int i_ = 0; i_ < 4; ++i_)                               \
        gload16(Ah + aoff[i_] + k0_, lds + (buf) * 32768 + i_ * 8192 + dst);       \
    _Pragma("unroll") for (int i_ = 0; i_ < 2; ++i_)                               \
        gload16(B + boff[i_] + k0_, lds + 65536 + (buf) * 16384 + i_ * 8192 + dst);\
} while (0)

    const int frd = (lane & 12) << 3;
    const int cb0 = (((lane >> 4) * 16)      ) ^ frd;
    const int cb1 = (((lane >> 4) * 16) + 64 ) ^ frd;
    const int arow = wr * 16384 + (lane & 15) * 128;
    const int brow = 65536 + (wc * 32 + (lane & 15)) * 128;

    f32x4 acc[8][2];
#pragma unroll
    for (int mi = 0; mi < 8; ++mi)
#pragma unroll
        for (int ni = 0; ni < 2; ++ni) acc[mi][ni] = (f32x4){0.f, 0.f, 0.f, 0.f};

    G2_STAGE(0, 0);
    G2_STAGE(1, 1);
    VMW(6);
    BARRIER();

    const int NT = IDIM / 64;   // 64
    int buf = 0;
    for (int kt = 0; kt < NT; ++kt) {
        const char* la = lds + buf * 32768 + arow;
        const char* lb = lds + buf * 16384 + brow;
        bf16x8 af[2][4], bfr[2][2];
        // S1
#pragma unroll
        for (int mi = 0; mi < 4; ++mi) {
            af[0][mi] = *(const bf16x8*)(la + mi * 2048 + cb0);
            af[1][mi] = *(const bf16x8*)(la + mi * 2048 + cb1);
        }
#pragma unroll
        for (int ni = 0; ni < 2; ++ni) {
            bfr[0][ni] = *(const bf16x8*)(lb + ni * 2048 + cb0);
            bfr[1][ni] = *(const bf16x8*)(lb + ni * 2048 + cb1);
        }
        LGKM0();
        __builtin_amdgcn_s_setprio(1);
#pragma unroll
        for (int ks = 0; ks < 2; ++ks)
#pragma unroll
            for (int mi = 0; mi < 4; ++mi)
#pragma unroll
                for (int ni = 0; ni < 2; ++ni)
                    acc[mi][ni] = __builtin_amdgcn_mfma_f32_16x16x32_bf16(af[ks][mi], bfr[ks][ni], acc[mi][ni], 0, 0, 0);
        __builtin_amdgcn_s_setprio(0);
        BARRIER();
        // S2: reload af(mi4-7), MFMA mi4-5
#pragma unroll
        for (int mi = 0; mi < 4; ++mi) {
            af[0][mi] = *(const bf16x8*)(la + (mi + 4) * 2048 + cb0);
            af[1][mi] = *(const bf16x8*)(la + (mi + 4) * 2048 + cb1);
        }
        LGKM0();
        __builtin_amdgcn_s_setprio(1);
#pragma unroll
        for (int ks = 0; ks < 2; ++ks)
#pragma unroll
            for (int mi = 0; mi < 2; ++mi)
#pragma unroll
                for (int ni = 0; ni < 2; ++ni)
                    acc[mi + 4][ni] = __builtin_amdgcn_mfma_f32_16x16x32_bf16(af[ks][mi], bfr[ks][ni], acc[mi + 4][ni], 0, 0, 0);
        __builtin_amdgcn_s_setprio(0);
        BARRIER();   // all reads of buf done
        // S3: stage kt+2, MFMA mi6-7, drain kt+1
        G2_STAGE(buf, (kt + 2) & (NT - 1));
        __builtin_amdgcn_s_setprio(1);
#pragma unroll
        for (int ks = 0; ks < 2; ++ks)
#pragma unroll
            for (int mi = 2; mi < 4; ++mi)
#pragma unroll
                for (int ni = 0; ni < 2; ++ni)
                    acc[mi + 4][ni] = __builtin_amdgcn_mfma_f32_16x16x32_bf16(af[ks][mi], bfr[ks][ni], acc[mi + 4][ni], 0, 0, 0);
        __builtin_amdgcn_s_setprio(0);
        VMW(6);
        BARRIER();
        buf ^= 1;
    }
    VMW(0);
#undef G2_STAGE

#pragma unroll
    for (int mi = 0; mi < 8; ++mi)
#pragma unroll
        for (int j = 0; j < 4; ++j) {
            int g = t0 + wr * 128 + mi * 16 + ((lane >> 4) << 2) + j;
            if (g < cnt) {
                int ent = list[g];
                int tok = ent & 0xFFFF;
                int sl  = ent >> 16;
                float w = wgt[(size_t)tok * NEXP + e];
                float* o = outP + (size_t)sl * T_TOK * HDIM + (size_t)tok * HDIM;
#pragma unroll
                for (int ni = 0; ni < 2; ++ni) {
                    int col = n0 + wc * 32 + ni * 16 + (lane & 15);
                    o[col] = w * acc[mi][ni][j];
                }
            }
        }
}

// ---------------- combine ----------------
__global__ __launch_bounds__(256) void combine_k(const float* __restrict__ p0,
                                                 const float* __restrict__ p1,
                                                 float* __restrict__ out, long n4) {
    long i      = (long)blockIdx.x * 256 + threadIdx.x;
    long stride = (long)gridDim.x * 256;
    const float4* a4 = (const float4*)p0;
    const float4* b4 = (const float4*)p1;
    float4* o4 = (float4*)out;
    for (long j = i; j < n4; j += stride) {
        float4 a = a4[j], b = b4[j];
        o4[j] = make_float4(a.x + b.x, a.y + b.y, a.z + b.z, a.w + b.w);
    }
}

extern "C" void kernel_launch(void* const* d_in, const int* in_sizes, int n_in,
                              void* d_out, int out_size, void* d_ws, size_t ws_size,
                              hipStream_t stream) {
    const float* hs  = (const float*)d_in[0];
    const float* rw  = (const float*)d_in[1];
    const float* ws  = (const float*)d_in[2];
    const float* w2s = (const float*)d_in[3];
    float* out = (float*)d_out;

    char* wsp = (char*)d_ws;
    unsigned short* hs_bf = (unsigned short*)(wsp);                 //  33,554,432
    unsigned short* w_bf  = (unsigned short*)(wsp + 33554432ULL);   // 268,435,456
    unsigned short* w2_bf = (unsigned short*)(wsp + 301989888ULL);  // 134,217,728
    unsigned short* h_bf  = (unsigned short*)(wsp + 436207616ULL);  // 150,994,944 (18432 x IDIM)
    float*          outP  = (float*)(wsp + 587202560ULL);           // 134,217,728
    float*          wgt   = (float*)(wsp + 721420288ULL);           //     262,144
    int*            counts = (int*)(wsp + 721682432ULL);
    int*            offs   = (int*)(wsp + 721682560ULL);
    int*            lists  = (int*)(wsp + 721682688ULL);            //     262,144
    int*            desc   = (int*)(wsp + 721944832ULL);            //         512
    int*            ntiles = (int*)(wsp + 721945344ULL);

    hipMemsetAsync(counts, 0, NEXP * sizeof(int), stream);
    cvt_k<<<2048, 256, 0, stream>>>(hs, hs_bf, (long)T_TOK * HDIM / 4);
    cvt_k<<<4096, 256, 0, stream>>>(ws, w_bf, (long)NEXP * 2 * IDIM * HDIM / 4);
    cvt_k<<<4096, 256, 0, stream>>>(w2s, w2_bf, (long)NEXP * HDIM * IDIM / 4);
    router_k<<<(T_TOK * 64) / 256, 256, 0, stream>>>(hs, rw, wgt, counts, lists);
    plan_k<<<1, 64, 0, stream>>>(counts, offs, desc, ntiles);

    gemm1_k<<<dim3(IDIM / 128, MAXT), 512, 131072, stream>>>(
        hs_bf, w_bf, h_bf, lists, counts, offs, desc, ntiles);
    gemm2_k<<<dim3(HDIM / 128, MAXT), 512, 98304, stream>>>(
        h_bf, w2_bf, wgt, outP, lists, counts, offs, desc, ntiles);
    combine_k<<<2048, 256, 0, stream>>>(outP, outP + (size_t)T_TOK * HDIM, out,
                                        (long)T_TOK * HDIM / 4);
}

// Round 6
// 1494.299 us; speedup vs baseline: 2.8409x; 1.0656x over previous
//
#include <hip/hip_runtime.h>
#include <cstdint>
#include <cstddef>

#define T_TOK 8192
#define HDIM  2048
#define IDIM  4096
#define NEXP  8
#define MAXT  72   // sum_e ceil(cnt_e/256) <= 16384/256 + 7 = 71

typedef __bf16 bf16x8 __attribute__((ext_vector_type(8)));
typedef float  f32x4  __attribute__((ext_vector_type(4)));

#define BARRIER() __builtin_amdgcn_s_barrier()
#define LGKM0()   do { asm volatile("s_waitcnt lgkmcnt(0)" ::: "memory"); __builtin_amdgcn_sched_barrier(0); } while (0)
#define VMW(n)    do { asm volatile("s_waitcnt vmcnt(" #n ")" ::: "memory"); } while (0)
#define PRIO1()   __builtin_amdgcn_s_setprio(1)
#define PRIO0()   __builtin_amdgcn_s_setprio(0)

__device__ __forceinline__ unsigned short f2bf(float f) {
    union { float f; unsigned u; } v; v.f = f;
    unsigned r = v.u + 0x7FFFu + ((v.u >> 16) & 1u);   // RNE
    return (unsigned short)(r >> 16);
}

__device__ __forceinline__ void gload16(const void* g, void* l) {
    __builtin_amdgcn_global_load_lds((__attribute__((address_space(1))) void*)g,
                                     (__attribute__((address_space(3))) void*)l,
                                     16, 0, 0);
}

// ---------------- router ----------------
__global__ __launch_bounds__(256) void router_k(const float* __restrict__ hs,
                                                const float* __restrict__ rw,
                                                float* __restrict__ wgt,
                                                int* __restrict__ counts,
                                                int* __restrict__ lists) {
    int gid  = blockIdx.x * 256 + threadIdx.x;
    int tok  = gid >> 6;
    int lane = threadIdx.x & 63;
    const float* x = hs + (size_t)tok * HDIM;

    float acc[NEXP];
#pragma unroll
    for (int e = 0; e < NEXP; ++e) acc[e] = 0.f;
    for (int h = lane; h < HDIM; h += 64) {
        float xv = x[h];
#pragma unroll
        for (int e = 0; e < NEXP; ++e) acc[e] = fmaf(xv, rw[e * HDIM + h], acc[e]);
    }
#pragma unroll
    for (int off = 32; off > 0; off >>= 1) {
#pragma unroll
        for (int e = 0; e < NEXP; ++e) acc[e] += __shfl_xor(acc[e], off, 64);
    }
    if (lane == 0) {
        float m = acc[0];
#pragma unroll
        for (int e = 1; e < NEXP; ++e) m = fmaxf(m, acc[e]);
        float p[NEXP]; float s = 0.f;
#pragma unroll
        for (int e = 0; e < NEXP; ++e) { p[e] = expf(acc[e] - m); s += p[e]; }
        float inv = 1.f / s;
        int i1 = 0;
#pragma unroll
        for (int e = 1; e < NEXP; ++e) if (acc[e] > acc[i1]) i1 = e;
        int i2 = -1;
#pragma unroll
        for (int e = 0; e < NEXP; ++e) if (e != i1 && (i2 < 0 || acc[e] > acc[i2])) i2 = e;
#pragma unroll
        for (int e = 0; e < NEXP; ++e)
            wgt[(size_t)tok * NEXP + e] = (e == i1 || e == i2) ? p[e] * inv : 0.f;
        int p1 = atomicAdd(&counts[i1], 1);
        lists[i1 * T_TOK + p1] = tok;                 // slot 0
        int p2 = atomicAdd(&counts[i2], 1);
        lists[i2 * T_TOK + p2] = (1 << 16) | tok;     // slot 1
    }
}

// ---------------- planner (256-row granularity) ----------------
__global__ void plan_k(const int* __restrict__ counts, int* __restrict__ offs,
                       int* __restrict__ desc, int* __restrict__ ntiles) {
    if (threadIdx.x == 0 && blockIdx.x == 0) {
        int off = 0, n = 0;
        for (int e = 0; e < NEXP; ++e) {
            offs[e] = off;
            int nt = (counts[e] + 255) >> 8;
            for (int t = 0; t < nt; ++t) desc[n++] = (e << 16) | t;
            off += nt * 256;
        }
        *ntiles = n;
    }
}

// ---------------- fp32 -> bf16 ----------------
__global__ __launch_bounds__(256) void cvt_k(const float* __restrict__ in,
                                             unsigned short* __restrict__ out, long n4) {
    long i      = (long)blockIdx.x * 256 + threadIdx.x;
    long stride = (long)gridDim.x * 256;
    const float4* in4 = (const float4*)in;
    ushort4* out4 = (ushort4*)out;
    for (long j = i; j < n4; j += stride) {
        float4 v = in4[j];
        ushort4 o;
        o.x = f2bf(v.x); o.y = f2bf(v.y); o.z = f2bf(v.z); o.w = f2bf(v.w);
        out4[j] = o;
    }
}

// ============ GEMM1: fused gate/up, BM=256 BN=128(g)+128(u), BK=64, 8 waves ============
// LDS 128 KiB: A [buf][4x8192] @0 ; Bg @65536+buf*16384 ; Bu @98304+buf*16384
// swizzle: byte-in-row ^= (row&7)<<4  (write via pre-swizzled global src, read via XOR'd col)
__global__ __launch_bounds__(512, 2) void gemm1_k(const unsigned short* __restrict__ A,
                                                  const unsigned short* __restrict__ Wall,
                                                  unsigned short* __restrict__ Hout,
                                                  const int* __restrict__ lists,
                                                  const int* __restrict__ counts,
                                                  const int* __restrict__ offs,
                                                  const int* __restrict__ desc,
                                                  const int* __restrict__ ntiles) {
    const int slot = blockIdx.y;
    if (slot >= *ntiles) return;
    const int dsc = desc[slot];
    const int e = dsc >> 16, tt = dsc & 0xFFFF;
    const int cnt = counts[e];
    const int t0 = tt * 256;
    const int* list = lists + e * T_TOK;
    const unsigned short* W = Wall + (size_t)e * 2 * IDIM * HDIM;
    const int hbase = offs[e];
    const int n0 = blockIdx.x * 128;

    extern __shared__ __align__(16) char lds[];

    const int tid  = threadIdx.x;
    const int lane = tid & 63;
    const int wid  = tid >> 6;
    const int wr   = wid >> 2;   // M half (128 rows)
    const int wc   = wid & 3;    // 32-col group (gate & up)

    // ---- staging: pre-swizzled global source, linear LDS dest ----
    const int prow = tid >> 3;                 // 0..63
    const int pcol = (tid & 7) * 16;           // byte within 128B row
    const int lcol = (pcol ^ ((prow & 7) << 4)) >> 1;   // element offset in K-chunk
    unsigned aoff[4];
#pragma unroll
    for (int i = 0; i < 4; ++i) {
        int g = t0 + i * 64 + prow;
        int tok = list[(g < cnt) ? g : t0] & 0xFFFF;
        aoff[i] = (unsigned)tok * HDIM + lcol;
    }
    unsigned goff[2], uoff[2];
#pragma unroll
    for (int i = 0; i < 2; ++i) {
        goff[i] = (unsigned)(n0 + i * 64 + prow) * HDIM + lcol;
        uoff[i] = (unsigned)(IDIM + n0 + i * 64 + prow) * HDIM + lcol;
    }
    const int dst = tid * 16;

#define G1_STAGE(buf, kt) do {                                                     \
    unsigned k0_ = (unsigned)(kt) * 64;                                            \
    _Pragma("unroll") for (int i_ = 0; i_ < 4; ++i_)                               \
        gload16(A + aoff[i_] + k0_, lds + (buf) * 32768 + i_ * 8192 + dst);        \
    _Pragma("unroll") for (int i_ = 0; i_ < 2; ++i_)                               \
        gload16(W + goff[i_] + k0_, lds + 65536 + (buf) * 16384 + i_ * 8192 + dst);\
    _Pragma("unroll") for (int i_ = 0; i_ < 2; ++i_)                               \
        gload16(W + uoff[i_] + k0_, lds + 98304 + (buf) * 16384 + i_ * 8192 + dst);\
} while (0)

    // ---- read-side swizzled column bytes ----
    const int frd = (lane & 7) << 4;
    const int cb0 = (((lane >> 4) * 16)     ) ^ frd;   // ks0: bytes 0-63
    const int cb1 = (((lane >> 4) * 16) | 64) ^ frd;   // ks1: bytes 64-127
    const int arow = wr * 16384 + (lane & 15) * 128;          // + mi*2048 + buf*32768
    const int brow = (wc * 32 + (lane & 15)) * 128;           // + ni*2048 (+ panel base)

    f32x4 accg[8][2], accu[8][2];
#pragma unroll
    for (int mi = 0; mi < 8; ++mi)
#pragma unroll
        for (int ni = 0; ni < 2; ++ni) {
            accg[mi][ni] = (f32x4){0.f, 0.f, 0.f, 0.f};
            accu[mi][ni] = (f32x4){0.f, 0.f, 0.f, 0.f};
        }

    G1_STAGE(0, 0);
    G1_STAGE(1, 1);
    VMW(8);
    BARRIER();

    const int NT = HDIM / 64;   // 32
    int buf = 0;
    for (int kt = 0; kt < NT; ++kt) {
        const char* la = lds + buf * 32768 + arow;
        const char* lg = lds + 65536 + buf * 16384 + brow;
        const char* lu = lds + 98304 + buf * 16384 + brow;
        bf16x8 af[4], bg[2], bu[2];
        // ---- P1: ks0, mi0-3 (+ B ks0) ----
#pragma unroll
        for (int mi = 0; mi < 4; ++mi) af[mi] = *(const bf16x8*)(la + mi * 2048 + cb0);
#pragma unroll
        for (int ni = 0; ni < 2; ++ni) {
            bg[ni] = *(const bf16x8*)(lg + ni * 2048 + cb0);
            bu[ni] = *(const bf16x8*)(lu + ni * 2048 + cb0);
        }
        LGKM0(); PRIO1();
#pragma unroll
        for (int mi = 0; mi < 4; ++mi)
#pragma unroll
            for (int ni = 0; ni < 2; ++ni) {
                accg[mi][ni] = __builtin_amdgcn_mfma_f32_16x16x32_bf16(af[mi], bg[ni], accg[mi][ni], 0, 0, 0);
                accu[mi][ni] = __builtin_amdgcn_mfma_f32_16x16x32_bf16(af[mi], bu[ni], accu[mi][ni], 0, 0, 0);
            }
        PRIO0();
        // ---- P2: ks0, mi4-7 ----
#pragma unroll
        for (int mi = 0; mi < 4; ++mi) af[mi] = *(const bf16x8*)(la + (mi + 4) * 2048 + cb0);
        LGKM0(); PRIO1();
#pragma unroll
        for (int mi = 0; mi < 4; ++mi)
#pragma unroll
            for (int ni = 0; ni < 2; ++ni) {
                accg[mi + 4][ni] = __builtin_amdgcn_mfma_f32_16x16x32_bf16(af[mi], bg[ni], accg[mi + 4][ni], 0, 0, 0);
                accu[mi + 4][ni] = __builtin_amdgcn_mfma_f32_16x16x32_bf16(af[mi], bu[ni], accu[mi + 4][ni], 0, 0, 0);
            }
        PRIO0();
        // ---- P3: ks1, mi0-3 (+ B ks1) ----
#pragma unroll
        for (int mi = 0; mi < 4; ++mi) af[mi] = *(const bf16x8*)(la + mi * 2048 + cb1);
#pragma unroll
        for (int ni = 0; ni < 2; ++ni) {
            bg[ni] = *(const bf16x8*)(lg + ni * 2048 + cb1);
            bu[ni] = *(const bf16x8*)(lu + ni * 2048 + cb1);
        }
        LGKM0(); PRIO1();
#pragma unroll
        for (int mi = 0; mi < 4; ++mi)
#pragma unroll
            for (int ni = 0; ni < 2; ++ni) {
                accg[mi][ni] = __builtin_amdgcn_mfma_f32_16x16x32_bf16(af[mi], bg[ni], accg[mi][ni], 0, 0, 0);
                accu[mi][ni] = __builtin_amdgcn_mfma_f32_16x16x32_bf16(af[mi], bu[ni], accu[mi][ni], 0, 0, 0);
            }
        PRIO0();
        // ---- P4: ks1, mi4-7 ; stage kt+2 ; drain kt+1 ----
#pragma unroll
        for (int mi = 0; mi < 4; ++mi) af[mi] = *(const bf16x8*)(la + (mi + 4) * 2048 + cb1);
        LGKM0();
        BARRIER();                      // all waves done reading buf
        G1_STAGE(buf, (kt + 2) & (NT - 1));
        PRIO1();
#pragma unroll
        for (int mi = 0; mi < 4; ++mi)
#pragma unroll
            for (int ni = 0; ni < 2; ++ni) {
                accg[mi + 4][ni] = __builtin_amdgcn_mfma_f32_16x16x32_bf16(af[mi], bg[ni], accg[mi + 4][ni], 0, 0, 0);
                accu[mi + 4][ni] = __builtin_amdgcn_mfma_f32_16x16x32_bf16(af[mi], bu[ni], accu[mi + 4][ni], 0, 0, 0);
            }
        PRIO0();
        VMW(8);                         // kt+1's loads (issued a full tile ago) done
        BARRIER();
        buf ^= 1;
    }
    VMW(0);
#undef G1_STAGE

#pragma unroll
    for (int mi = 0; mi < 8; ++mi)
#pragma unroll
        for (int ni = 0; ni < 2; ++ni)
#pragma unroll
            for (int j = 0; j < 4; ++j) {
                int row = hbase + t0 + wr * 128 + mi * 16 + ((lane >> 4) << 2) + j;
                int col = n0 + wc * 32 + ni * 16 + (lane & 15);
                float g = accg[mi][ni][j], u = accu[mi][ni][j];
                float hv = (g / (1.f + expf(-g))) * u;
                Hout[(size_t)row * IDIM + col] = f2bf(hv);
            }
}

// ============ GEMM2: BM=256 BN=256 BK=64, 8 waves, scatter epilogue ============
// LDS 128 KiB: A [buf][4x8192] @0 ; B [buf][4x8192] @65536
__global__ __launch_bounds__(512, 2) void gemm2_k(const unsigned short* __restrict__ Ah,
                                                  const unsigned short* __restrict__ Ball,
                                                  const float* __restrict__ wgt,
                                                  float* __restrict__ outP,
                                                  const int* __restrict__ lists,
                                                  const int* __restrict__ counts,
                                                  const int* __restrict__ offs,
                                                  const int* __restrict__ desc,
                                                  const int* __restrict__ ntiles) {
    const int slot = blockIdx.y;
    if (slot >= *ntiles) return;
    const int dsc = desc[slot];
    const int e = dsc >> 16, tt = dsc & 0xFFFF;
    const int cnt = counts[e];
    const int t0 = tt * 256;
    const int* list = lists + e * T_TOK;
    const unsigned short* B = Ball + (size_t)e * HDIM * IDIM;
    const int hbase = offs[e];
    const int n0 = blockIdx.x * 256;

    extern __shared__ __align__(16) char lds[];

    const int tid  = threadIdx.x;
    const int lane = tid & 63;
    const int wid  = tid >> 6;
    const int wr   = wid >> 2;
    const int wc   = wid & 3;    // 64-col group

    const int prow = tid >> 3;
    const int pcol = (tid & 7) * 16;
    const int lcol = (pcol ^ ((prow & 7) << 4)) >> 1;
    unsigned aoff[4], boff[4];
#pragma unroll
    for (int i = 0; i < 4; ++i) {
        aoff[i] = (unsigned)(hbase + t0 + i * 64 + prow) * IDIM + lcol;
        boff[i] = (unsigned)(n0 + i * 64 + prow) * IDIM + lcol;
    }
    const int dst = tid * 16;

#define G2_STAGE(buf, kt) do {                                                     \
    unsigned k0_ = (unsigned)(kt) * 64;                                            \
    _Pragma("unroll") for (int i_ = 0; i_ < 4; ++i_)                               \
        gload16(Ah + aoff[i_] + k0_, lds + (buf) * 32768 + i_ * 8192 + dst);       \
    _Pragma("unroll") for (int i_ = 0; i_ < 4; ++i_)                               \
        gload16(B + boff[i_] + k0_, lds + 65536 + (buf) * 32768 + i_ * 8192 + dst);\
} while (0)

    const int frd = (lane & 7) << 4;
    const int cb0 = (((lane >> 4) * 16)     ) ^ frd;
    const int cb1 = (((lane >> 4) * 16) | 64) ^ frd;
    const int arow = wr * 16384 + (lane & 15) * 128;
    const int brow = (wc * 64 + (lane & 15)) * 128;

    f32x4 acc[8][4];
#pragma unroll
    for (int mi = 0; mi < 8; ++mi)
#pragma unroll
        for (int ni = 0; ni < 4; ++ni) acc[mi][ni] = (f32x4){0.f, 0.f, 0.f, 0.f};

    G2_STAGE(0, 0);
    G2_STAGE(1, 1);
    VMW(8);
    BARRIER();

    const int NT = IDIM / 64;   // 64
    int buf = 0;
    for (int kt = 0; kt < NT; ++kt) {
        const char* la = lds + buf * 32768 + arow;
        const char* lb = lds + 65536 + buf * 32768 + brow;
        bf16x8 af[4], bfr[4];
        // P1: ks0, mi0-3 (+ B ks0)
#pragma unroll
        for (int mi = 0; mi < 4; ++mi) af[mi] = *(const bf16x8*)(la + mi * 2048 + cb0);
#pragma unroll
        for (int ni = 0; ni < 4; ++ni) bfr[ni] = *(const bf16x8*)(lb + ni * 2048 + cb0);
        LGKM0(); PRIO1();
#pragma unroll
        for (int mi = 0; mi < 4; ++mi)
#pragma unroll
            for (int ni = 0; ni < 4; ++ni)
                acc[mi][ni] = __builtin_amdgcn_mfma_f32_16x16x32_bf16(af[mi], bfr[ni], acc[mi][ni], 0, 0, 0);
        PRIO0();
        // P2: ks0, mi4-7
#pragma unroll
        for (int mi = 0; mi < 4; ++mi) af[mi] = *(const bf16x8*)(la + (mi + 4) * 2048 + cb0);
        LGKM0(); PRIO1();
#pragma unroll
        for (int mi = 0; mi < 4; ++mi)
#pragma unroll
            for (int ni = 0; ni < 4; ++ni)
                acc[mi + 4][ni] = __builtin_amdgcn_mfma_f32_16x16x32_bf16(af[mi], bfr[ni], acc[mi + 4][ni], 0, 0, 0);
        PRIO0();
        // P3: ks1, mi0-3 (+ B ks1)
#pragma unroll
        for (int mi = 0; mi < 4; ++mi) af[mi] = *(const bf16x8*)(la + mi * 2048 + cb1);
#pragma unroll
        for (int ni = 0; ni < 4; ++ni) bfr[ni] = *(const bf16x8*)(lb + ni * 2048 + cb1);
        LGKM0(); PRIO1();
#pragma unroll
        for (int mi = 0; mi < 4; ++mi)
#pragma unroll
            for (int ni = 0; ni < 4; ++ni)
                acc[mi][ni] = __builtin_amdgcn_mfma_f32_16x16x32_bf16(af[mi], bfr[ni], acc[mi][ni], 0, 0, 0);
        PRIO0();
        // P4: ks1, mi4-7 ; stage kt+2 ; drain kt+1
#pragma unroll
        for (int mi = 0; mi < 4; ++mi) af[mi] = *(const bf16x8*)(la + (mi + 4) * 2048 + cb1);
        LGKM0();
        BARRIER();
        G2_STAGE(buf, (kt + 2) & (NT - 1));
        PRIO1();
#pragma unroll
        for (int mi = 0; mi < 4; ++mi)
#pragma unroll
            for (int ni = 0; ni < 4; ++ni)
                acc[mi + 4][ni] = __builtin_amdgcn_mfma_f32_16x16x32_bf16(af[mi], bfr[ni], acc[mi + 4][ni], 0, 0, 0);
        PRIO0();
        VMW(8);
        BARRIER();
        buf ^= 1;
    }
    VMW(0);
#undef G2_STAGE

#pragma unroll
    for (int mi = 0; mi < 8; ++mi)
#pragma unroll
        for (int j = 0; j < 4; ++j) {
            int g = t0 + wr * 128 + mi * 16 + ((lane >> 4) << 2) + j;
            if (g < cnt) {
                int ent = list[g];
                int tok = ent & 0xFFFF;
                int sl  = ent >> 16;
                float w = wgt[(size_t)tok * NEXP + e];
                float* o = outP + (size_t)sl * T_TOK * HDIM + (size_t)tok * HDIM;
#pragma unroll
                for (int ni = 0; ni < 4; ++ni) {
                    int col = n0 + wc * 64 + ni * 16 + (lane & 15);
                    o[col] = w * acc[mi][ni][j];
                }
            }
        }
}

// ---------------- combine ----------------
__global__ __launch_bounds__(256) void combine_k(const float* __restrict__ p0,
                                                 const float* __restrict__ p1,
                                                 float* __restrict__ out, long n4) {
    long i      = (long)blockIdx.x * 256 + threadIdx.x;
    long stride = (long)gridDim.x * 256;
    const float4* a4 = (const float4*)p0;
    const float4* b4 = (const float4*)p1;
    float4* o4 = (float4*)out;
    for (long j = i; j < n4; j += stride) {
        float4 a = a4[j], b = b4[j];
        o4[j] = make_float4(a.x + b.x, a.y + b.y, a.z + b.z, a.w + b.w);
    }
}

extern "C" void kernel_launch(void* const* d_in, const int* in_sizes, int n_in,
                              void* d_out, int out_size, void* d_ws, size_t ws_size,
                              hipStream_t stream) {
    const float* hs  = (const float*)d_in[0];
    const float* rw  = (const float*)d_in[1];
    const float* ws  = (const float*)d_in[2];
    const float* w2s = (const float*)d_in[3];
    float* out = (float*)d_out;

    char* wsp = (char*)d_ws;
    unsigned short* hs_bf = (unsigned short*)(wsp);                 //  33,554,432
    unsigned short* w_bf  = (unsigned short*)(wsp + 33554432ULL);   // 268,435,456
    unsigned short* w2_bf = (unsigned short*)(wsp + 301989888ULL);  // 134,217,728
    unsigned short* h_bf  = (unsigned short*)(wsp + 436207616ULL);  // 150,994,944 (18432 x IDIM)
    float*          outP  = (float*)(wsp + 587202560ULL);           // 134,217,728
    float*          wgt   = (float*)(wsp + 721420288ULL);           //     262,144
    int*            counts = (int*)(wsp + 721682432ULL);
    int*            offs   = (int*)(wsp + 721682560ULL);
    int*            lists  = (int*)(wsp + 721682688ULL);            //     262,144
    int*            desc   = (int*)(wsp + 721944832ULL);            //         512
    int*            ntiles = (int*)(wsp + 721945344ULL);

    hipMemsetAsync(counts, 0, NEXP * sizeof(int), stream);
    cvt_k<<<2048, 256, 0, stream>>>(hs, hs_bf, (long)T_TOK * HDIM / 4);
    cvt_k<<<4096, 256, 0, stream>>>(ws, w_bf, (long)NEXP * 2 * IDIM * HDIM / 4);
    cvt_k<<<4096, 256, 0, stream>>>(w2s, w2_bf, (long)NEXP * HDIM * IDIM / 4);
    router_k<<<(T_TOK * 64) / 256, 256, 0, stream>>>(hs, rw, wgt, counts, lists);
    plan_k<<<1, 64, 0, stream>>>(counts, offs, desc, ntiles);

    gemm1_k<<<dim3(IDIM / 128, MAXT), 512, 131072, stream>>>(
        hs_bf, w_bf, h_bf, lists, counts, offs, desc, ntiles);
    gemm2_k<<<dim3(HDIM / 256, MAXT), 512, 131072, stream>>>(
        h_bf, w2_bf, wgt, outP, lists, counts, offs, desc, ntiles);
    combine_k<<<2048, 256, 0, stream>>>(outP, outP + (size_t)T_TOK * HDIM, out,
                                        (long)T_TOK * HDIM / 4);
}